// Round 11
// baseline (348.834 us; speedup 1.0000x reference)
//
#include <hip/hip_runtime.h>
#include <cmath>

#define EMB 1024
#define NH 16
#define HD 64
#define FF_DIM 4096
#define BB 2
#define TT 2048
#define NTOK (BB * TT)
#define QKVS 3072
#define SC2F 0.18033688011112042f  // log2(e) / sqrt(64), folded into Q at QKV epilogue

typedef _Float16 f16x8 __attribute__((ext_vector_type(8)));
typedef _Float16 f16x4 __attribute__((ext_vector_type(4)));
typedef float f32x4 __attribute__((ext_vector_type(4)));

// fast tanh-GELU, NaN-safe: x*e/(e+1) written as x - x/(e+1)
__device__ __forceinline__ float gelu_fast(float x) {
    float u = x * (1.f + 0.044715f * x * x);
    float e = exp2f(u * 2.302118751f);  // 2 * 0.7978845608 * log2(e)
    return x - x / (e + 1.f);
}

// ---------------- LayerNorm: one block (256 thr) per token, EMB=1024 ----------------
template <typename TIN>
__global__ __launch_bounds__(256) void ln_kernel(const TIN* __restrict__ xin,
                                                 _Float16* __restrict__ out,
                                                 const float* __restrict__ g,
                                                 const float* __restrict__ bv) {
    int tid = threadIdx.x;
    size_t base = (size_t)blockIdx.x * EMB;
    float v[4];
#pragma unroll
    for (int i = 0; i < 4; ++i) v[i] = (float)xin[base + i * 256 + tid];
    float s = v[0] + v[1] + v[2] + v[3];
    float ss = v[0] * v[0] + v[1] * v[1] + v[2] * v[2] + v[3] * v[3];
#pragma unroll
    for (int off = 32; off > 0; off >>= 1) {
        s += __shfl_down(s, off);
        ss += __shfl_down(ss, off);
    }
    __shared__ float red[8];
    int wave = tid >> 6;
    if ((tid & 63) == 0) { red[wave] = s; red[4 + wave] = ss; }
    __syncthreads();
    s = red[0] + red[1] + red[2] + red[3];
    ss = red[4] + red[5] + red[6] + red[7];
    float mu = s * (1.0f / EMB);
    float var = ss * (1.0f / EMB) - mu * mu;
    float rstd = rsqrtf(var + 1e-5f);
#pragma unroll
    for (int i = 0; i < 4; ++i) {
        int idx = i * 256 + tid;
        float y = (v[i] - mu) * rstd * g[idx] + bv[idx];
        out[base + idx] = (_Float16)y;
    }
}

// ---------------- fused: LN1 + wq/wk/wv/wo cast+transpose + qkv bias ----------------
// grid 8204: [0,4096) weight tiles, [4096,4108) bias, [4108,8204) LN1 tokens
__global__ __launch_bounds__(256) void prep0_kernel(const float* __restrict__ x,
                                                    _Float16* __restrict__ xn,
                                                    const float* __restrict__ ln1_g,
                                                    const float* __restrict__ ln1_b,
                                                    const float* __restrict__ wq,
                                                    const float* __restrict__ wk,
                                                    const float* __restrict__ wv,
                                                    const float* __restrict__ wo,
                                                    const float* __restrict__ bq,
                                                    const float* __restrict__ bk,
                                                    const float* __restrict__ bv,
                                                    _Float16* __restrict__ wqkvT,
                                                    _Float16* __restrict__ woT,
                                                    float* __restrict__ qkvbias) {
    __shared__ float tile[32][33];
    int blk = blockIdx.x;
    int tid = threadIdx.x;
    if (blk >= 4108) {  // ---- LN1 ----
        size_t base = (size_t)(blk - 4108) * EMB;
        float v[4];
#pragma unroll
        for (int i = 0; i < 4; ++i) v[i] = x[base + i * 256 + tid];
        float s = v[0] + v[1] + v[2] + v[3];
        float ss = v[0] * v[0] + v[1] * v[1] + v[2] * v[2] + v[3] * v[3];
#pragma unroll
        for (int off = 32; off > 0; off >>= 1) {
            s += __shfl_down(s, off);
            ss += __shfl_down(ss, off);
        }
        float* red = &tile[0][0];
        int wave = tid >> 6;
        if ((tid & 63) == 0) { red[wave] = s; red[4 + wave] = ss; }
        __syncthreads();
        s = red[0] + red[1] + red[2] + red[3];
        ss = red[4] + red[5] + red[6] + red[7];
        float mu = s * (1.0f / EMB);
        float var = ss * (1.0f / EMB) - mu * mu;
        float rstd = rsqrtf(var + 1e-5f);
#pragma unroll
        for (int i = 0; i < 4; ++i) {
            int idx = i * 256 + tid;
            xn[base + idx] = (_Float16)((v[i] - mu) * rstd * ln1_g[idx] + ln1_b[idx]);
        }
        return;
    }
    if (blk >= 4096) {  // ---- fused qkv bias ----
        int i = (blk - 4096) * 256 + tid;  // 0..3071
        qkvbias[i] = i < 1024 ? bq[i] : (i < 2048 ? bk[i - 1024] : bv[i - 2048]);
        return;
    }
    // ---- weight cast+transpose ----
    const float* W;
    _Float16* Wt;
    int t = blk & 1023;
    int z = blk >> 10;
    if (z == 0) { W = wq; Wt = wqkvT; }
    else if (z == 1) { W = wk; Wt = wqkvT + 1024 * 1024; }
    else if (z == 2) { W = wv; Wt = wqkvT + 2 * 1024 * 1024; }
    else { W = wo; Wt = woT; }
    int bx = (t & 31) * 32, by = (t >> 5) * 32;
    int tx = tid & 31, ty = tid >> 5;
#pragma unroll
    for (int i = 0; i < 32; i += 8)
        tile[ty + i][tx] = W[(size_t)(by + ty + i) * EMB + bx + tx];
    __syncthreads();
#pragma unroll
    for (int i = 0; i < 32; i += 8)
        Wt[(size_t)(bx + ty + i) * EMB + by + tx] = (_Float16)tile[tx][ty + i];
}

// ---------------- prep2: w1 (1024x4096) + w2 (4096x1024) cast+transpose -------------
__global__ __launch_bounds__(256) void prep2_kernel(const float* __restrict__ w1,
                                                    const float* __restrict__ w2,
                                                    _Float16* __restrict__ w1T,
                                                    _Float16* __restrict__ w2T) {
    int b = blockIdx.x;
    const float* W;
    _Float16* Wt;
    int K, N, t;
    if (b < 4096) { W = w1; Wt = w1T; K = 1024; N = 4096; t = b; }
    else { W = w2; Wt = w2T; K = 4096; N = 1024; t = b - 4096; }
    int ntx = N >> 5;
    int bx = (t % ntx) * 32, by = (t / ntx) * 32;
    __shared__ float tile[32][33];
    int tx = threadIdx.x & 31, ty = threadIdx.x >> 5;
#pragma unroll
    for (int i = 0; i < 32; i += 8)
        tile[ty + i][tx] = W[(size_t)(by + ty + i) * N + bx + tx];
    __syncthreads();
#pragma unroll
    for (int i = 0; i < 32; i += 8)
        Wt[(size_t)(bx + ty + i) * K + by + tx] = (_Float16)tile[tx][ty + i];
}

// ---------------- V transpose (48MB-fallback only) ----------------------------------
__global__ __launch_bounds__(256) void vT_kernel(const _Float16* __restrict__ qkv,
                                                 _Float16* __restrict__ VtG) {
    __shared__ _Float16 tile[64][72];
    int tid = threadIdx.x;
    int bh = blockIdx.y;
    int b = bh >> 4, h = bh & 15;
    int t0 = blockIdx.x * 64;
    const _Float16* src = qkv + (size_t)b * TT * QKVS + 2048 + h * HD;
    int r = tid >> 3;
    int c8 = (tid & 7) * 8;
#pragma unroll
    for (int p = 0; p < 2; ++p)
        *(f16x8*)(&tile[r + p * 32][c8]) =
            *(const f16x8*)(src + (size_t)(t0 + r + p * 32) * QKVS + c8);
    __syncthreads();
#pragma unroll
    for (int p = 0; p < 2; ++p) {
        int d = r + p * 32;
        f16x8 v;
#pragma unroll
        for (int j = 0; j < 8; ++j) v[j] = tile[c8 + j][d];
        *(f16x8*)(VtG + ((size_t)bh * HD + d) * TT + t0 + c8) = v;
    }
}

// ---------------- m97-style GEMM 128x128 with XOR-swizzled LDS ----------------------
// MODE 6: QKV fused (Q scaled by SC2F; V blocks written transposed to VtG if vtg)
// MODE 1: out f16 = gelu_fast(acc+bias)                  (FF1)  [fallback path only]
template <int MODE>
__global__ __launch_bounds__(256) void gemm_f16t(const _Float16* __restrict__ A,
                                                 const _Float16* __restrict__ Bt,
                                                 const float* __restrict__ bias,
                                                 void* __restrict__ outp,
                                                 void* __restrict__ vtg,
                                                 int M, int N, int K, int lda, int ldb) {
    __shared__ _Float16 As[128][64];  // NO padding: global_load_lds lane ordering
    __shared__ _Float16 Bs[128][64];
    int tid = threadIdx.x;
    int lane = tid & 63, w = tid >> 6;
    int quad = lane >> 4, l15 = lane & 15;
    int wm = (w >> 1) * 64, wn = (w & 1) * 64;
    int bM = blockIdx.y * 128, bN = blockIdx.x * 128;
    int lr = lane >> 3;
    int lcs = ((lane & 7) ^ lr) * 8;  // swizzled source k-chunk
    int sw = l15 & 7;
    f32x4 acc[4][4] = {};

    const _Float16* Abase = A + (size_t)(bM + w * 32 + lr) * lda + lcs;
    const _Float16* Bbase = Bt + (size_t)(bN + w * 32 + lr) * ldb + lcs;

    for (int kt = 0; kt < K; kt += 64) {
#pragma unroll
        for (int i = 0; i < 4; ++i) {
            __builtin_amdgcn_global_load_lds(
                (const __attribute__((address_space(1))) void*)(Abase + (size_t)(i * 8) * lda + kt),
                (__attribute__((address_space(3))) void*)(&As[w * 32 + i * 8][0]), 16, 0, 0);
            __builtin_amdgcn_global_load_lds(
                (const __attribute__((address_space(1))) void*)(Bbase + (size_t)(i * 8) * ldb + kt),
                (__attribute__((address_space(3))) void*)(&Bs[w * 32 + i * 8][0]), 16, 0, 0);
        }
        __syncthreads();
#pragma unroll
        for (int ks = 0; ks < 2; ++ks) {
            f16x8 af[4], bf[4];
#pragma unroll
            for (int i = 0; i < 4; ++i) {
                int sc = ((ks * 4 + quad) ^ sw) * 8;
                af[i] = *(const f16x8*)(&As[wm + i * 16 + l15][sc]);
                bf[i] = *(const f16x8*)(&Bs[wn + i * 16 + l15][sc]);
            }
#pragma unroll
            for (int i = 0; i < 4; ++i)
#pragma unroll
                for (int j = 0; j < 4; ++j)
                    acc[i][j] = __builtin_amdgcn_mfma_f32_16x16x32_f16(af[i], bf[j], acc[i][j], 0, 0, 0);
        }
        __syncthreads();
    }

    if (MODE == 6 && vtg != nullptr && bN >= 2048) {
        int bb = bM >> 11;
        int tbase = (bM & 2047) + wm;
#pragma unroll
        for (int i = 0; i < 4; ++i)
#pragma unroll
            for (int j = 0; j < 4; ++j) {
                int hd = bN - 2048 + wn + j * 16;
                int col = 2048 + hd + l15;
                _Float16* dst = (_Float16*)vtg +
                    (((size_t)(bb * 16 + (hd >> 6)) * 64) + (hd & 63) + l15) * TT +
                    tbase + i * 16 + quad * 4;
                f16x4 ov;
#pragma unroll
                for (int r = 0; r < 4; ++r) ov[r] = (_Float16)(acc[i][j][r] + bias[col]);
                *(f16x4*)dst = ov;
            }
        return;
    }

#pragma unroll
    for (int i = 0; i < 4; ++i)
#pragma unroll
        for (int j = 0; j < 4; ++j)
#pragma unroll
            for (int r = 0; r < 4; ++r) {
                int row = bM + wm + i * 16 + quad * 4 + r;
                int col = bN + wn + j * 16 + l15;
                size_t idx = (size_t)row * N + col;
                float vv = acc[i][j][r] + bias[col];
                if (MODE == 6) {
                    if (bN < 1024) vv *= SC2F;
                    ((_Float16*)outp)[idx] = (_Float16)vv;
                } else {  // MODE 1
                    ((_Float16*)outp)[idx] = (_Float16)gelu_fast(vv);
                }
            }
}

// ---------------- gemm128d: 128x128 dbuf 2-phase, 256 thr, 2 blk/CU -----------------
// The structure that made gemm_ff2 hit ~890 TF (R7->R9 within-session A/B): 64KB dbuf
// LDS -> 2 blocks resident/CU, so the sibling block's MFMA covers this block's
// vmcnt(0) drain. Per K-tile: {stage next tile (8 global_load_lds) -> ds_read+MFMA
// from current -> vmcnt(0) -> raw s_barrier}. Flat grid + bijective XCD swizzle
// (nwg % 8 == 0 for all our shapes). 2x2 waves, per-wave 64x64 out.
// MODE 0: out f16 = gelu_fast(acc+bias)                          (FF1)
// MODE 1: QKV fused epilogue (Q scale, V->VtG transposed, bias)   (QKV)
#define G128_STAGE(OB, TN)                                                               \
    {                                                                                    \
        size_t ko = (size_t)(TN) * 64;                                                   \
        _Pragma("unroll") for (int i = 0; i < 4; ++i) {                                  \
            __builtin_amdgcn_global_load_lds(                                            \
                (const __attribute__((address_space(1))) void*)(Ab + (size_t)(i * 8) * lda + ko), \
                (__attribute__((address_space(3))) void*)(&As[OB][w * 32 + i * 8][0]), 16, 0, 0); \
            __builtin_amdgcn_global_load_lds(                                            \
                (const __attribute__((address_space(1))) void*)(Bb + (size_t)(i * 8) * ldb + ko), \
                (__attribute__((address_space(3))) void*)(&Bs[OB][w * 32 + i * 8][0]), 16, 0, 0); \
        }                                                                                \
    }

template <int MODE>
__global__ __launch_bounds__(256) void gemm128d(const _Float16* __restrict__ A,
                                                const _Float16* __restrict__ Bt,
                                                const float* __restrict__ bias,
                                                void* __restrict__ outp,
                                                void* __restrict__ vtg,
                                                int M, int N, int K, int lda, int ldb) {
    __shared__ _Float16 As[2][128][64];
    __shared__ _Float16 Bs[2][128][64];
    int tid = threadIdx.x;
    int lane = tid & 63, w = tid >> 6;   // w 0..3
    int quad = lane >> 4, l15 = lane & 15;
    int wr = (w >> 1) * 64, wc = (w & 1) * 64;  // 2x2 wave grid; per-wave 64x64
    int gx = N >> 7;
    int nwg = gridDim.x;
    int bid = blockIdx.x;
    int cpx = nwg >> 3;
    int sbid = (bid & 7) * cpx + (bid >> 3);  // bijective XCD swizzle (nwg%8==0)
    int bN = (sbid % gx) * 128;
    int bM = (sbid / gx) * 128;
    int lr = lane >> 3;
    int lcs = ((lane & 7) ^ lr) * 8;
    int sw = l15 & 7;
    f32x4 acc[4][4] = {};
    f16x8 af[4][2], bf[4][2];

    const _Float16* Ab = A + (size_t)(bM + w * 32 + lr) * lda + lcs;
    const _Float16* Bb = Bt + (size_t)(bN + w * 32 + lr) * ldb + lcs;
    const int NT = K >> 6;  // 16 for K=1024

    G128_STAGE(0, 0);
    asm volatile("s_waitcnt vmcnt(0)" ::: "memory");
    __builtin_amdgcn_s_barrier();

    int cur = 0;
    for (int t = 0; t < NT; ++t) {
        int nxt = cur ^ 1;
        int tn = (t + 1 < NT) ? t + 1 : 0;  // last iter: dummy re-stage (never read)
        G128_STAGE(nxt, tn);
#pragma unroll
        for (int i = 0; i < 4; ++i) {
#pragma unroll
            for (int ks = 0; ks < 2; ++ks)
                af[i][ks] = *(const f16x8*)(&As[cur][wr + i * 16 + l15][((ks * 4 + quad) ^ sw) * 8]);
        }
#pragma unroll
        for (int jj = 0; jj < 4; ++jj) {
#pragma unroll
            for (int ks = 0; ks < 2; ++ks)
                bf[jj][ks] = *(const f16x8*)(&Bs[cur][wc + jj * 16 + l15][((ks * 4 + quad) ^ sw) * 8]);
        }
#pragma unroll
        for (int ks = 0; ks < 2; ++ks)
#pragma unroll
            for (int i = 0; i < 4; ++i)
#pragma unroll
                for (int jj = 0; jj < 4; ++jj)
                    acc[i][jj] = __builtin_amdgcn_mfma_f32_16x16x32_f16(af[i][ks], bf[jj][ks], acc[i][jj], 0, 0, 0);
        asm volatile("s_waitcnt vmcnt(0)" ::: "memory");
        __builtin_amdgcn_s_barrier();
        cur = nxt;
    }

    if (MODE == 1 && vtg != nullptr && bN >= 2048) {  // QKV V-blocks: transposed to VtG
        int bb = bM >> 11;
#pragma unroll
        for (int i = 0; i < 4; ++i)
#pragma unroll
            for (int jj = 0; jj < 4; ++jj) {
                int hd = bN - 2048 + wc + jj * 16;
                int col = 2048 + hd + l15;
                int tb = (bM & 2047) + wr + i * 16 + quad * 4;
                _Float16* dst = (_Float16*)vtg +
                    (((size_t)(bb * 16 + (hd >> 6)) * 64) + (hd & 63) + l15) * TT + tb;
                f16x4 ov;
#pragma unroll
                for (int r = 0; r < 4; ++r) ov[r] = (_Float16)(acc[i][jj][r] + bias[col]);
                *(f16x4*)dst = ov;
            }
        return;
    }

#pragma unroll
    for (int i = 0; i < 4; ++i)
#pragma unroll
        for (int jj = 0; jj < 4; ++jj)
#pragma unroll
            for (int r = 0; r < 4; ++r) {
                int row = bM + wr + i * 16 + quad * 4 + r;
                int col = bN + wc + jj * 16 + l15;
                size_t idx = (size_t)row * N + col;
                float vv = acc[i][jj][r] + bias[col];
                if (MODE == 1) {
                    if (bN < 1024) vv *= SC2F;
                    ((_Float16*)outp)[idx] = (_Float16)vv;
                } else {  // MODE 0: FF1 gelu
                    ((_Float16*)outp)[idx] = (_Float16)gelu_fast(vv);
                }
            }
}

// ---------------- FF2: 128x128-tile K-split-2 2-phase GEMM, 256 thr, 2 blk/CU -------
// Flat grid 512 = 2 blocks/CU (64KB dbuf LDS): sibling block's MFMA covers this
// block's vmcnt(0) drain. XCD-aware mapping: xcd = bid&7; z-slice zz = xcd>>2 (4 XCDs
// per K-half), M-quarter mq = xcd&3, n-fastest within XCD -> per-XCD resident set =
// 4MB w2T z-slice + 512KB A-panel (reused across 8 consecutive n-blocks) ~ L2-fit.
// Partials (f16) -> p0/p1 at S0/S2 (attnout/x2, both dead; NO overlap with ff1 S4..S8
// or w2T S3 -- the R8 bug), summed by ff2_reduce.
__global__ __launch_bounds__(256) void gemm_ff2(const _Float16* __restrict__ A,
                                                const _Float16* __restrict__ Bt,
                                                _Float16* __restrict__ p0,
                                                _Float16* __restrict__ p1,
                                                int M, int N, int K, int lda, int ldb) {
    __shared__ _Float16 As[2][128][64];
    __shared__ _Float16 Bs[2][128][64];
    int tid = threadIdx.x;
    int lane = tid & 63, w = tid >> 6;   // w 0..3
    int quad = lane >> 4, l15 = lane & 15;
    int wr = (w >> 1) * 64, wc = (w & 1) * 64;  // 2x2 wave grid; per-wave 64x64
    int bid = blockIdx.x;                // 0..511
    int xcd = bid & 7;
    int j = bid >> 3;                    // 0..63
    int zz = xcd >> 2;                   // 0..1: K-half per XCD group
    int mq = xcd & 3;                    // M-quarter
    int n = j & 7;                       // n fastest: consecutive blocks share A-panel
    int m = (j >> 3) + mq * 8;           // 0..31
    int bM = m * 128, bN = n * 128;
    int kz = zz * 2048;
    int lr = lane >> 3;
    int lcs = ((lane & 7) ^ lr) * 8;
    int sw = l15 & 7;
    f32x4 acc[4][4] = {};
    f16x8 af[4][2], bf[4][2];

    const _Float16* Ab = A + (size_t)(bM + w * 32 + lr) * lda + kz + lcs;
    const _Float16* Bb = Bt + (size_t)(bN + w * 32 + lr) * ldb + kz + lcs;
    const int NT = 32;  // K=2048 per slice

    G128_STAGE(0, 0);
    asm volatile("s_waitcnt vmcnt(0)" ::: "memory");
    __builtin_amdgcn_s_barrier();

    int cur = 0;
    for (int t = 0; t < NT; ++t) {
        int nxt = cur ^ 1;
        int tn = (t + 1 < NT) ? t + 1 : 0;  // last iter: dummy re-stage (never read)
        G128_STAGE(nxt, tn);
#pragma unroll
        for (int i = 0; i < 4; ++i) {
#pragma unroll
            for (int ks = 0; ks < 2; ++ks)
                af[i][ks] = *(const f16x8*)(&As[cur][wr + i * 16 + l15][((ks * 4 + quad) ^ sw) * 8]);
        }
#pragma unroll
        for (int jj = 0; jj < 4; ++jj) {
#pragma unroll
            for (int ks = 0; ks < 2; ++ks)
                bf[jj][ks] = *(const f16x8*)(&Bs[cur][wc + jj * 16 + l15][((ks * 4 + quad) ^ sw) * 8]);
        }
#pragma unroll
        for (int ks = 0; ks < 2; ++ks)
#pragma unroll
            for (int i = 0; i < 4; ++i)
#pragma unroll
                for (int jj = 0; jj < 4; ++jj)
                    acc[i][jj] = __builtin_amdgcn_mfma_f32_16x16x32_f16(af[i][ks], bf[jj][ks], acc[i][jj], 0, 0, 0);
        asm volatile("s_waitcnt vmcnt(0)" ::: "memory");
        __builtin_amdgcn_s_barrier();
        cur = nxt;
    }

    _Float16* pout = zz ? p1 : p0;
#pragma unroll
    for (int i = 0; i < 4; ++i)
#pragma unroll
        for (int jj = 0; jj < 4; ++jj)
#pragma unroll
            for (int r = 0; r < 4; ++r) {
                int row = bM + wr + i * 16 + quad * 4 + r;
                int col = bN + wc + jj * 16 + l15;
                pout[(size_t)row * N + col] = (_Float16)acc[i][jj][r];
            }
}

// ---------------- GEMM 128Mx64N, single-buffer (R4 version), XOR swizzle ------------
// MODE 2: out f16 = resid(f32) + alpha*(acc+bias)          (attn proj -> xmid)
// MODE 4: out f32 = acc                                    (FF2 pass a, fallback)
// MODE 5: out f32 = resid(f16) + alpha*(out + acc + bias)  (FF2 pass b, fallback)
template <int MODE>
__global__ __launch_bounds__(256) void gemm64(const _Float16* __restrict__ A,
                                              const _Float16* __restrict__ Bt,
                                              const float* __restrict__ bias,
                                              void* __restrict__ outp,
                                              const void* __restrict__ residp,
                                              const float* __restrict__ alphap,
                                              int M, int N, int K, int lda, int ldb) {
    __shared__ _Float16 As[128][64];
    __shared__ _Float16 Bs[64][64];
    int tid = threadIdx.x;
    int lane = tid & 63, w = tid >> 6;
    int quad = lane >> 4, l15 = lane & 15;
    int wm = w * 32;
    int bM = blockIdx.y * 128, bN = blockIdx.x * 64;
    int lr = lane >> 3;
    int lcs = ((lane & 7) ^ lr) * 8;
    int sw = l15 & 7;
    f32x4 acc[2][4] = {};

    const _Float16* Abase = A + (size_t)(bM + w * 32 + lr) * lda + lcs;
    const _Float16* Bbase = Bt + (size_t)(bN + w * 16 + lr) * ldb + lcs;

    for (int kt = 0; kt < K; kt += 64) {
#pragma unroll
        for (int i = 0; i < 4; ++i)
            __builtin_amdgcn_global_load_lds(
                (const __attribute__((address_space(1))) void*)(Abase + (size_t)(i * 8) * lda + kt),
                (__attribute__((address_space(3))) void*)(&As[w * 32 + i * 8][0]), 16, 0, 0);
#pragma unroll
        for (int i = 0; i < 2; ++i)
            __builtin_amdgcn_global_load_lds(
                (const __attribute__((address_space(1))) void*)(Bbase + (size_t)(i * 8) * ldb + kt),
                (__attribute__((address_space(3))) void*)(&Bs[w * 16 + i * 8][0]), 16, 0, 0);
        __syncthreads();
#pragma unroll
        for (int ks = 0; ks < 2; ++ks) {
            int sc = ((ks * 4 + quad) ^ sw) * 8;
            f16x8 af[2], bf[4];
#pragma unroll
            for (int i = 0; i < 2; ++i)
                af[i] = *(const f16x8*)(&As[wm + i * 16 + l15][sc]);
#pragma unroll
            for (int j = 0; j < 4; ++j)
                bf[j] = *(const f16x8*)(&Bs[j * 16 + l15][sc]);
#pragma unroll
            for (int i = 0; i < 2; ++i)
#pragma unroll
                for (int j = 0; j < 4; ++j)
                    acc[i][j] = __builtin_amdgcn_mfma_f32_16x16x32_f16(af[i], bf[j], acc[i][j], 0, 0, 0);
        }
        __syncthreads();
    }

    float alpha = 0.f;
    if (MODE == 2 || MODE == 5) alpha = alphap[0];
#pragma unroll
    for (int i = 0; i < 2; ++i)
#pragma unroll
        for (int j = 0; j < 4; ++j)
#pragma unroll
            for (int r = 0; r < 4; ++r) {
                int row = bM + wm + i * 16 + quad * 4 + r;
                int col = bN + j * 16 + l15;
                size_t idx = (size_t)row * N + col;
                if (MODE == 4) {
                    ((float*)outp)[idx] = acc[i][j][r];
                } else if (MODE == 2) {
                    float vv = acc[i][j][r] + bias[col];
                    float rsd = ((const float*)residp)[idx];
                    ((_Float16*)outp)[idx] = (_Float16)(rsd + alpha * vv);
                } else {  // MODE 5
                    float vv = acc[i][j][r] + bias[col];
                    float prev = ((float*)outp)[idx];
                    float rsd = (float)((const _Float16*)residp)[idx];
                    ((float*)outp)[idx] = rsd + alpha * (prev + vv);
                }
            }
}

// ---------------- FF2 reduce: d_out = xmid + alpha*(p0+p1+b2), vectorized x8 --------
__global__ __launch_bounds__(256) void ff2_reduce_kernel(const _Float16* __restrict__ p0,
                                                         const _Float16* __restrict__ p1,
                                                         const _Float16* __restrict__ xmid,
                                                         const float* __restrict__ b2,
                                                         const float* __restrict__ alphap,
                                                         float* __restrict__ out) {
    int i = (blockIdx.x * 256 + threadIdx.x) * 8;
    float alpha = alphap[0];
    f16x8 a = *(const f16x8*)(p0 + i);
    f16x8 b = *(const f16x8*)(p1 + i);
    f16x8 xm = *(const f16x8*)(xmid + i);
    int col = i & 1023;
#pragma unroll
    for (int k = 0; k < 8; ++k)
        out[i + k] = (float)xm[k] + alpha * ((float)a[k] + (float)b[k] + b2[col + k]);
}

// ---------------- MFMA flash attention: balanced 8-wave, 2 q-tiles/block ------------
#define QT 64
#define NEG_BIG (-1e30f)
__global__ __launch_bounds__(512) void attn_mfma_kernel(const _Float16* __restrict__ qkv,
                                                        const _Float16* __restrict__ VtG,
                                                        _Float16* __restrict__ O) {
    __shared__ _Float16 Ks[64][72];
    __shared__ _Float16 Vt[64][72];
    __shared__ _Float16 Ps[8][16][68];
    int tid = threadIdx.x;
    int lane = tid & 63, w = tid >> 6;     // w in 0..7
    int quad = lane >> 4, l15 = lane & 15;
    int bh = blockIdx.x;
    int b = bh >> 4, h = bh & 15;
    int y = blockIdx.y;                    // 0..15
    int seg = w >> 2, ws = w & 3;          // seg 0: long q-tile, seg 1: short
    int qt = seg ? y : (31 - y);
    int q0 = qt * QT;
    int ntw = qt + 1;                      // K-tiles THIS wave computes
    int ntmax = 32 - y;                    // K-tiles staged (= long wave's ntw)
    const _Float16* Qh = qkv + (size_t)b * TT * QKVS + h * HD;
    const _Float16* Kh = Qh + 1024;
    const _Float16* Vrows = VtG + (size_t)bh * HD * TT;

    int m0 = q0 + ws * 16;
    f16x8 aq0 = *(const f16x8*)(Qh + (size_t)(m0 + l15) * QKVS + quad * 8);
    f16x8 aq1 = *(const f16x8*)(Qh + (size_t)(m0 + l15) * QKVS + 32 + quad * 8);

    f32x4 Oacc[4] = {};
    float lrow[4] = {0.f, 0.f, 0.f, 0.f};

    // staging: 512 threads cover 64 rows x 64 cols, one f16x8 each per buffer
    int rr = tid >> 3;                     // 0..63
    int c8 = (tid & 7) * 8;
    const _Float16* Kp = Kh + (size_t)rr * QKVS + c8;
    const _Float16* Vp = Vrows + (size_t)rr * TT + c8;

    f16x8 kreg = *(const f16x8*)(Kp);
    f16x8 vreg = *(const f16x8*)(Vp);

    for (int t = 0; t < ntmax; ++t) {
        int t0 = t * 64;
        __syncthreads();
        *(f16x8*)(&Ks[rr][c8]) = kreg;
        *(f16x8*)(&Vt[rr][c8]) = vreg;
        __syncthreads();
        if (t + 1 < ntmax) {
            kreg = *(const f16x8*)(Kp + (size_t)(t0 + 64) * QKVS);
            vreg = *(const f16x8*)(Vp + t0 + 64);
        }
        if (t >= ntw) continue;           // short-seg waves: stage+barrier only

        f32x4 Sacc[4] = {};
        __builtin_amdgcn_s_setprio(1);
#pragma unroll
        for (int nc = 0; nc < 4; ++nc) {
            f16x8 bk0 = *(const f16x8*)(&Ks[nc * 16 + l15][quad * 8]);
            f16x8 bk1 = *(const f16x8*)(&Ks[nc * 16 + l15][32 + quad * 8]);
            Sacc[nc] = __builtin_amdgcn_mfma_f32_16x16x32_f16(aq0, bk0, Sacc[nc], 0, 0, 0);
            Sacc[nc] = __builtin_amdgcn_mfma_f32_16x16x32_f16(aq1, bk1, Sacc[nc], 0, 0, 0);
        }
        __builtin_amdgcn_s_setprio(0);

        if (t0 == q0) {  // diagonal tile: causal mask
#pragma unroll
            for (int nc = 0; nc < 4; ++nc) {
                int key = t0 + nc * 16 + l15;
#pragma unroll
                for (int i = 0; i < 4; ++i)
                    if (key > m0 + quad * 4 + i) Sacc[nc][i] = NEG_BIG;
            }
        }

        // P = exp2(S) (no max subtraction), accumulate per-lane l
#pragma unroll
        for (int nc = 0; nc < 4; ++nc)
#pragma unroll
            for (int i = 0; i < 4; ++i) {
                float p = exp2f(Sacc[nc][i]);
                lrow[i] += p;
                Ps[w][quad * 4 + i][nc * 16 + l15] = (_Float16)p;
            }
        __asm__ __volatile__("s_waitcnt lgkmcnt(0)" ::: "memory");  // wave-local roundtrip

        f16x8 ap0 = *(const f16x8*)(&Ps[w][l15][quad * 8]);
        f16x8 ap1 = *(const f16x8*)(&Ps[w][l15][32 + quad * 8]);
        __builtin_amdgcn_s_setprio(1);
#pragma unroll
        for (int nc = 0; nc < 4; ++nc) {
            int d = nc * 16 + l15;
            f16x8 bv0 = *(const f16x8*)(&Vt[d][quad * 8]);
            f16x8 bv1 = *(const f16x8*)(&Vt[d][32 + quad * 8]);
            Oacc[nc] = __builtin_amdgcn_mfma_f32_16x16x32_f16(ap0, bv0, Oacc[nc], 0, 0, 0);
            Oacc[nc] = __builtin_amdgcn_mfma_f32_16x16x32_f16(ap1, bv1, Oacc[nc], 0, 0, 0);
        }
        __builtin_amdgcn_s_setprio(0);
    }

#pragma unroll
    for (int off = 1; off < 16; off <<= 1)
#pragma unroll
        for (int i = 0; i < 4; ++i) lrow[i] += __shfl_xor(lrow[i], off);
#pragma unroll
    for (int i = 0; i < 4; ++i) lrow[i] = 1.0f / lrow[i];
    _Float16* Oh = O + (size_t)b * TT * EMB + h * HD;
#pragma unroll
    for (int nc = 0; nc < 4; ++nc)
#pragma unroll
        for (int i = 0; i < 4; ++i) {
            int row = m0 + quad * 4 + i;
            Oh[(size_t)row * EMB + nc * 16 + l15] = (_Float16)(Oacc[nc][i] * lrow[i]);
        }
}

extern "C" void kernel_launch(void* const* d_in, const int* in_sizes, int n_in,
                              void* d_out, int out_size, void* d_ws, size_t ws_size,
                              hipStream_t stream) {
    const float* x = (const float*)d_in[0];
    const float* wq = (const float*)d_in[1];
    const float* bq = (const float*)d_in[2];
    const float* wk = (const float*)d_in[3];
    const float* bk = (const float*)d_in[4];
    const float* wv = (const float*)d_in[5];
    const float* bv = (const float*)d_in[6];
    const float* wo = (const float*)d_in[7];
    const float* bo = (const float*)d_in[8];
    const float* w1 = (const float*)d_in[9];
    const float* b1 = (const float*)d_in[10];
    const float* w2 = (const float*)d_in[11];
    const float* b2 = (const float*)d_in[12];
    const float* ln1_g = (const float*)d_in[13];
    const float* ln1_b = (const float*)d_in[14];
    const float* ln2_g = (const float*)d_in[15];
    const float* ln2_b = (const float*)d_in[16];
    const float* alpha_attn = (const float*)d_in[17];
    const float* alpha_ff = (const float*)d_in[18];

    const size_t SL = (size_t)8 * 1024 * 1024;
    char* ws = (char*)d_ws;
    _Float16* xn = (_Float16*)(ws);
    _Float16* qkv = (_Float16*)(ws + SL);
    _Float16* wqkvT = (_Float16*)(ws + 4 * SL);
    float* qkvbias = (float*)(ws + 4 * SL + 6 * 1024 * 1024);
    _Float16* attnout = (_Float16*)(ws);
    _Float16* xmid = (_Float16*)(ws + SL);
    _Float16* x2 = (_Float16*)(ws + 2 * SL);
    _Float16* w1T = (_Float16*)(ws);
    _Float16* w2T = (_Float16*)(ws + 3 * SL);
    _Float16* ff1 = (_Float16*)(ws + 4 * SL);
    bool bigws = ws_size >= (size_t)64 * 1024 * 1024;
    // bigws: VtG=S5, woT=S6 (no aliasing with wqkvT during QKV, fused vT OK).
    // fallback (48MB): VtG=S4 (overwrites wqkvT AFTER QKV via separate vT kernel),
    //                  woT=S5; fused vT disabled (would alias wqkvT mid-GEMM).
    _Float16* VtG = bigws ? (_Float16*)(ws + 5 * SL) : (_Float16*)(ws + 4 * SL);
    _Float16* woT = bigws ? (_Float16*)(ws + 6 * SL) : (_Float16*)(ws + 5 * SL);
    // FF2 partials: S0 (attnout dead) and S2 (x2 dead after FF1). Do NOT use S5/S6:
    // ff1 is 32MB spanning S4..S8 and is gemm_ff2's live A operand (R8 bug).
    _Float16* part0 = (_Float16*)(ws);
    _Float16* part1 = (_Float16*)(ws + 2 * SL);

    prep0_kernel<<<8204, 256, 0, stream>>>(x, xn, ln1_g, ln1_b, wq, wk, wv, wo,
                                           bq, bk, bv, wqkvT, woT, qkvbias);

    if (bigws) {
        gemm128d<1><<<(QKVS / 128) * (NTOK / 128), 256, 0, stream>>>(
            xn, wqkvT, qkvbias, qkv, (void*)VtG, NTOK, QKVS, EMB, EMB, EMB);
    } else {
        gemm_f16t<6><<<dim3(QKVS / 128, NTOK / 128), 256, 0, stream>>>(
            xn, wqkvT, qkvbias, qkv, nullptr, NTOK, QKVS, EMB, EMB, EMB);
        vT_kernel<<<dim3(TT / 64, BB * NH), 256, 0, stream>>>(qkv, VtG);
    }

    attn_mfma_kernel<<<dim3(BB * NH, TT / QT / 2), 512, 0, stream>>>(qkv, VtG, attnout);

    gemm64<2><<<dim3(EMB / 64, NTOK / 128), 256, 0, stream>>>(
        attnout, woT, bo, xmid, x, alpha_attn, NTOK, EMB, EMB, EMB, EMB);

    ln_kernel<_Float16><<<NTOK, 256, 0, stream>>>(xmid, x2, ln2_g, ln2_b);

    prep2_kernel<<<8192, 256, 0, stream>>>(w1, w2, w1T, w2T);

    if (bigws) {
        gemm128d<0><<<(FF_DIM / 128) * (NTOK / 128), 256, 0, stream>>>(
            x2, w1T, b1, ff1, nullptr, NTOK, FF_DIM, EMB, EMB, EMB);
        gemm_ff2<<<512, 256, 0, stream>>>(
            ff1, w2T, part0, part1, NTOK, EMB, FF_DIM, FF_DIM, FF_DIM);
        ff2_reduce_kernel<<<NTOK * EMB / 8 / 256, 256, 0, stream>>>(
            part0, part1, xmid, b2, alpha_ff, (float*)d_out);
    } else {
        const int NC = 2048;
        for (int hh = 0; hh < 2; ++hh) {
            const _Float16* w1Th = w1T + (size_t)hh * NC * EMB;
            const _Float16* w2Th = w2T + (size_t)hh * NC;
            gemm_f16t<1><<<dim3(NC / 128, NTOK / 128), 256, 0, stream>>>(
                x2, w1Th, b1 + hh * NC, ff1, nullptr, NTOK, NC, EMB, EMB, EMB);
            if (hh == 0)
                gemm64<4><<<dim3(EMB / 64, NTOK / 128), 256, 0, stream>>>(
                    ff1, w2Th, nullptr, d_out, nullptr, nullptr, NTOK, EMB, NC, NC, FF_DIM);
            else
                gemm64<5><<<dim3(EMB / 64, NTOK / 128), 256, 0, stream>>>(
                    ff1, w2Th, b2, d_out, xmid, alpha_ff, NTOK, EMB, NC, NC, FF_DIM);
        }
    }
}

// Round 12
// 337.917 us; speedup vs baseline: 1.0323x; 1.0323x over previous
//
#include <hip/hip_runtime.h>
#include <cmath>

#define EMB 1024
#define NH 16
#define HD 64
#define FF_DIM 4096
#define BB 2
#define TT 2048
#define NTOK (BB * TT)
#define QKVS 3072
#define SC2F 0.18033688011112042f  // log2(e) / sqrt(64), folded into Q at QKV epilogue

typedef _Float16 f16x8 __attribute__((ext_vector_type(8)));
typedef _Float16 f16x4 __attribute__((ext_vector_type(4)));
typedef float f32x4 __attribute__((ext_vector_type(4)));

// fast tanh-GELU, NaN-safe: x*e/(e+1) written as x - x/(e+1)
__device__ __forceinline__ float gelu_fast(float x) {
    float u = x * (1.f + 0.044715f * x * x);
    float e = exp2f(u * 2.302118751f);  // 2 * 0.7978845608 * log2(e)
    return x - x / (e + 1.f);
}

// ---------------- LayerNorm: one block (256 thr) per token, EMB=1024 ----------------
template <typename TIN>
__global__ __launch_bounds__(256) void ln_kernel(const TIN* __restrict__ xin,
                                                 _Float16* __restrict__ out,
                                                 const float* __restrict__ g,
                                                 const float* __restrict__ bv) {
    int tid = threadIdx.x;
    size_t base = (size_t)blockIdx.x * EMB;
    float v[4];
#pragma unroll
    for (int i = 0; i < 4; ++i) v[i] = (float)xin[base + i * 256 + tid];
    float s = v[0] + v[1] + v[2] + v[3];
    float ss = v[0] * v[0] + v[1] * v[1] + v[2] * v[2] + v[3] * v[3];
#pragma unroll
    for (int off = 32; off > 0; off >>= 1) {
        s += __shfl_down(s, off);
        ss += __shfl_down(ss, off);
    }
    __shared__ float red[8];
    int wave = tid >> 6;
    if ((tid & 63) == 0) { red[wave] = s; red[4 + wave] = ss; }
    __syncthreads();
    s = red[0] + red[1] + red[2] + red[3];
    ss = red[4] + red[5] + red[6] + red[7];
    float mu = s * (1.0f / EMB);
    float var = ss * (1.0f / EMB) - mu * mu;
    float rstd = rsqrtf(var + 1e-5f);
#pragma unroll
    for (int i = 0; i < 4; ++i) {
        int idx = i * 256 + tid;
        float y = (v[i] - mu) * rstd * g[idx] + bv[idx];
        out[base + idx] = (_Float16)y;
    }
}

// ---------------- fused: LN1 + wq/wk/wv/wo cast+transpose + qkv bias ----------------
// grid 8204: [0,4096) weight tiles, [4096,4108) bias, [4108,8204) LN1 tokens
__global__ __launch_bounds__(256) void prep0_kernel(const float* __restrict__ x,
                                                    _Float16* __restrict__ xn,
                                                    const float* __restrict__ ln1_g,
                                                    const float* __restrict__ ln1_b,
                                                    const float* __restrict__ wq,
                                                    const float* __restrict__ wk,
                                                    const float* __restrict__ wv,
                                                    const float* __restrict__ wo,
                                                    const float* __restrict__ bq,
                                                    const float* __restrict__ bk,
                                                    const float* __restrict__ bv,
                                                    _Float16* __restrict__ wqkvT,
                                                    _Float16* __restrict__ woT,
                                                    float* __restrict__ qkvbias) {
    __shared__ float tile[32][33];
    int blk = blockIdx.x;
    int tid = threadIdx.x;
    if (blk >= 4108) {  // ---- LN1 ----
        size_t base = (size_t)(blk - 4108) * EMB;
        float v[4];
#pragma unroll
        for (int i = 0; i < 4; ++i) v[i] = x[base + i * 256 + tid];
        float s = v[0] + v[1] + v[2] + v[3];
        float ss = v[0] * v[0] + v[1] * v[1] + v[2] * v[2] + v[3] * v[3];
#pragma unroll
        for (int off = 32; off > 0; off >>= 1) {
            s += __shfl_down(s, off);
            ss += __shfl_down(ss, off);
        }
        float* red = &tile[0][0];
        int wave = tid >> 6;
        if ((tid & 63) == 0) { red[wave] = s; red[4 + wave] = ss; }
        __syncthreads();
        s = red[0] + red[1] + red[2] + red[3];
        ss = red[4] + red[5] + red[6] + red[7];
        float mu = s * (1.0f / EMB);
        float var = ss * (1.0f / EMB) - mu * mu;
        float rstd = rsqrtf(var + 1e-5f);
#pragma unroll
        for (int i = 0; i < 4; ++i) {
            int idx = i * 256 + tid;
            xn[base + idx] = (_Float16)((v[i] - mu) * rstd * ln1_g[idx] + ln1_b[idx]);
        }
        return;
    }
    if (blk >= 4096) {  // ---- fused qkv bias ----
        int i = (blk - 4096) * 256 + tid;  // 0..3071
        qkvbias[i] = i < 1024 ? bq[i] : (i < 2048 ? bk[i - 1024] : bv[i - 2048]);
        return;
    }
    // ---- weight cast+transpose ----
    const float* W;
    _Float16* Wt;
    int t = blk & 1023;
    int z = blk >> 10;
    if (z == 0) { W = wq; Wt = wqkvT; }
    else if (z == 1) { W = wk; Wt = wqkvT + 1024 * 1024; }
    else if (z == 2) { W = wv; Wt = wqkvT + 2 * 1024 * 1024; }
    else { W = wo; Wt = woT; }
    int bx = (t & 31) * 32, by = (t >> 5) * 32;
    int tx = tid & 31, ty = tid >> 5;
#pragma unroll
    for (int i = 0; i < 32; i += 8)
        tile[ty + i][tx] = W[(size_t)(by + ty + i) * EMB + bx + tx];
    __syncthreads();
#pragma unroll
    for (int i = 0; i < 32; i += 8)
        Wt[(size_t)(bx + ty + i) * EMB + by + tx] = (_Float16)tile[tx][ty + i];
}

// ---------------- prep2: w1 (1024x4096) + w2 (4096x1024) cast+transpose -------------
__global__ __launch_bounds__(256) void prep2_kernel(const float* __restrict__ w1,
                                                    const float* __restrict__ w2,
                                                    _Float16* __restrict__ w1T,
                                                    _Float16* __restrict__ w2T) {
    int b = blockIdx.x;
    const float* W;
    _Float16* Wt;
    int K, N, t;
    if (b < 4096) { W = w1; Wt = w1T; K = 1024; N = 4096; t = b; }
    else { W = w2; Wt = w2T; K = 4096; N = 1024; t = b - 4096; }
    int ntx = N >> 5;
    int bx = (t % ntx) * 32, by = (t / ntx) * 32;
    __shared__ float tile[32][33];
    int tx = threadIdx.x & 31, ty = threadIdx.x >> 5;
#pragma unroll
    for (int i = 0; i < 32; i += 8)
        tile[ty + i][tx] = W[(size_t)(by + ty + i) * N + bx + tx];
    __syncthreads();
#pragma unroll
    for (int i = 0; i < 32; i += 8)
        Wt[(size_t)(bx + ty + i) * K + by + tx] = (_Float16)tile[tx][ty + i];
}

// ---------------- V transpose (48MB-fallback only) ----------------------------------
__global__ __launch_bounds__(256) void vT_kernel(const _Float16* __restrict__ qkv,
                                                 _Float16* __restrict__ VtG) {
    __shared__ _Float16 tile[64][72];
    int tid = threadIdx.x;
    int bh = blockIdx.y;
    int b = bh >> 4, h = bh & 15;
    int t0 = blockIdx.x * 64;
    const _Float16* src = qkv + (size_t)b * TT * QKVS + 2048 + h * HD;
    int r = tid >> 3;
    int c8 = (tid & 7) * 8;
#pragma unroll
    for (int p = 0; p < 2; ++p)
        *(f16x8*)(&tile[r + p * 32][c8]) =
            *(const f16x8*)(src + (size_t)(t0 + r + p * 32) * QKVS + c8);
    __syncthreads();
#pragma unroll
    for (int p = 0; p < 2; ++p) {
        int d = r + p * 32;
        f16x8 v;
#pragma unroll
        for (int j = 0; j < 8; ++j) v[j] = tile[c8 + j][d];
        *(f16x8*)(VtG + ((size_t)bh * HD + d) * TT + t0 + c8) = v;
    }
}

// ---------------- m97-style GEMM 128x128 with XOR-swizzled LDS ----------------------
// MODE 6: QKV fused (Q scaled by SC2F; V blocks written transposed to VtG if vtg)
// MODE 1: out f16 = gelu_fast(acc+bias)                  (FF1)  [fallback path only]
template <int MODE>
__global__ __launch_bounds__(256) void gemm_f16t(const _Float16* __restrict__ A,
                                                 const _Float16* __restrict__ Bt,
                                                 const float* __restrict__ bias,
                                                 void* __restrict__ outp,
                                                 void* __restrict__ vtg,
                                                 int M, int N, int K, int lda, int ldb) {
    __shared__ _Float16 As[128][64];  // NO padding: global_load_lds lane ordering
    __shared__ _Float16 Bs[128][64];
    int tid = threadIdx.x;
    int lane = tid & 63, w = tid >> 6;
    int quad = lane >> 4, l15 = lane & 15;
    int wm = (w >> 1) * 64, wn = (w & 1) * 64;
    int bM = blockIdx.y * 128, bN = blockIdx.x * 128;
    int lr = lane >> 3;
    int lcs = ((lane & 7) ^ lr) * 8;  // swizzled source k-chunk
    int sw = l15 & 7;
    f32x4 acc[4][4] = {};

    const _Float16* Abase = A + (size_t)(bM + w * 32 + lr) * lda + lcs;
    const _Float16* Bbase = Bt + (size_t)(bN + w * 32 + lr) * ldb + lcs;

    for (int kt = 0; kt < K; kt += 64) {
#pragma unroll
        for (int i = 0; i < 4; ++i) {
            __builtin_amdgcn_global_load_lds(
                (const __attribute__((address_space(1))) void*)(Abase + (size_t)(i * 8) * lda + kt),
                (__attribute__((address_space(3))) void*)(&As[w * 32 + i * 8][0]), 16, 0, 0);
            __builtin_amdgcn_global_load_lds(
                (const __attribute__((address_space(1))) void*)(Bbase + (size_t)(i * 8) * ldb + kt),
                (__attribute__((address_space(3))) void*)(&Bs[w * 32 + i * 8][0]), 16, 0, 0);
        }
        __syncthreads();
#pragma unroll
        for (int ks = 0; ks < 2; ++ks) {
            f16x8 af[4], bf[4];
#pragma unroll
            for (int i = 0; i < 4; ++i) {
                int sc = ((ks * 4 + quad) ^ sw) * 8;
                af[i] = *(const f16x8*)(&As[wm + i * 16 + l15][sc]);
                bf[i] = *(const f16x8*)(&Bs[wn + i * 16 + l15][sc]);
            }
#pragma unroll
            for (int i = 0; i < 4; ++i)
#pragma unroll
                for (int j = 0; j < 4; ++j)
                    acc[i][j] = __builtin_amdgcn_mfma_f32_16x16x32_f16(af[i], bf[j], acc[i][j], 0, 0, 0);
        }
        __syncthreads();
    }

    if (MODE == 6 && vtg != nullptr && bN >= 2048) {
        int bb = bM >> 11;
        int tbase = (bM & 2047) + wm;
#pragma unroll
        for (int i = 0; i < 4; ++i)
#pragma unroll
            for (int j = 0; j < 4; ++j) {
                int hd = bN - 2048 + wn + j * 16;
                int col = 2048 + hd + l15;
                _Float16* dst = (_Float16*)vtg +
                    (((size_t)(bb * 16 + (hd >> 6)) * 64) + (hd & 63) + l15) * TT +
                    tbase + i * 16 + quad * 4;
                f16x4 ov;
#pragma unroll
                for (int r = 0; r < 4; ++r) ov[r] = (_Float16)(acc[i][j][r] + bias[col]);
                *(f16x4*)dst = ov;
            }
        return;
    }

#pragma unroll
    for (int i = 0; i < 4; ++i)
#pragma unroll
        for (int j = 0; j < 4; ++j)
#pragma unroll
            for (int r = 0; r < 4; ++r) {
                int row = bM + wm + i * 16 + quad * 4 + r;
                int col = bN + wn + j * 16 + l15;
                size_t idx = (size_t)row * N + col;
                float vv = acc[i][j][r] + bias[col];
                if (MODE == 6) {
                    if (bN < 1024) vv *= SC2F;
                    ((_Float16*)outp)[idx] = (_Float16)vv;
                } else {  // MODE 1
                    ((_Float16*)outp)[idx] = (_Float16)gelu_fast(vv);
                }
            }
}

// ---------------- 256x256 single-buffer GEMM, 512 thr, 2 blk/CU ---------------------
// R11 lesson: 128d tile doubled FETCH (72MB) -> tile reuse and TLP must come together.
// Single-buffered 256^2 = 64KB LDS -> 2 blocks/CU (16 waves): sibling block's 64-MFMA
// per-wave compute covers this block's stage drain (m97-style implicit wave overlap;
// guide m105: 792 TF at 256^2 single-buffer vs our dbuf-1blk 663 TF). Per K-tile:
// {stage (8 glds) -> __syncthreads -> 64 MFMA -> __syncthreads}. XOR LDS swizzle
// (0 bank conflicts), bijective XCD swizzle.
// MODE 0: out f16 = gelu_fast(acc+bias)                          (FF1)
// MODE 1: QKV fused epilogue (Q scale, V->VtG transposed, bias)   (QKV)
#define STAGE1(TN, I)                                                                    \
    {                                                                                    \
        size_t ko = (size_t)(TN) * 64;                                                   \
        __builtin_amdgcn_global_load_lds(                                                \
            (const __attribute__((address_space(1))) void*)(Ab + (size_t)((I) * 8) * lda + ko), \
            (__attribute__((address_space(3))) void*)(&As[w * 32 + (I) * 8][0]), 16, 0, 0); \
        __builtin_amdgcn_global_load_lds(                                                \
            (const __attribute__((address_space(1))) void*)(Bb + (size_t)((I) * 8) * ldb + ko), \
            (__attribute__((address_space(3))) void*)(&Bs[w * 32 + (I) * 8][0]), 16, 0, 0); \
    }
#define RD_A1(I, KS) (*(const f16x8*)(&As[wr * 128 + (I) * 16 + l15][(((KS)*4 + quad) ^ sw) * 8]))
#define RD_B1(J, KS) (*(const f16x8*)(&Bs[wc * 64 + (J) * 16 + l15][(((KS)*4 + quad) ^ sw) * 8]))
#define MMQ(I0, J0)                                                                      \
    _Pragma("unroll") for (int ks = 0; ks < 2; ++ks) {                                   \
        _Pragma("unroll") for (int ii = 0; ii < 4; ++ii) {                               \
            _Pragma("unroll") for (int jj = 0; jj < 2; ++jj)                             \
                acc[(I0) + ii][(J0) + jj] = __builtin_amdgcn_mfma_f32_16x16x32_f16(      \
                    af[ii][ks], bf[(J0) + jj][ks], acc[(I0) + ii][(J0) + jj], 0, 0, 0);  \
        }                                                                                \
    }

template <int MODE>
__global__ __launch_bounds__(512, 2) void gemm256(const _Float16* __restrict__ A,
                                                  const _Float16* __restrict__ Bt,
                                                  const float* __restrict__ bias,
                                                  void* __restrict__ outp,
                                                  void* __restrict__ vtg,
                                                  int M, int N, int K, int lda, int ldb) {
    __shared__ _Float16 As[256][64];
    __shared__ _Float16 Bs[256][64];
    int tid = threadIdx.x;
    int lane = tid & 63, w = tid >> 6;   // w 0..7
    int quad = lane >> 4, l15 = lane & 15;
    int wr = w >> 2, wc = w & 3;         // 2x4 wave grid; per-wave out 128x64
    // XCD-bijective block swizzle (grid size divisible by 8 for our shapes)
    int gx = gridDim.x;
    int nwg = gx * gridDim.y;
    int bid = blockIdx.y * gx + blockIdx.x;
    int cpx = nwg >> 3;
    int sbid = (bid & 7) * cpx + (bid >> 3);
    int bN = (sbid % gx) * 256;
    int bM = (sbid / gx) * 256;
    int lr = lane >> 3;
    int lcs = ((lane & 7) ^ lr) * 8;     // swizzled source k-chunk
    int sw = l15 & 7;
    f32x4 acc[8][4] = {};
    f16x8 af[4][2], bf[4][2];

    const _Float16* Ab = A + (size_t)(bM + w * 32 + lr) * lda + lcs;
    const _Float16* Bb = Bt + (size_t)(bN + w * 32 + lr) * ldb + lcs;
    const int NT = K >> 6;  // K-tiles (16 for K=1024)

    for (int t = 0; t < NT; ++t) {
#pragma unroll
        for (int i = 0; i < 4; ++i) STAGE1(t, i);
        __syncthreads();
#pragma unroll
        for (int i = 0; i < 4; ++i) {
            af[i][0] = RD_A1(i, 0);
            af[i][1] = RD_A1(i, 1);
        }
        bf[0][0] = RD_B1(0, 0); bf[0][1] = RD_B1(0, 1);
        bf[1][0] = RD_B1(1, 0); bf[1][1] = RD_B1(1, 1);
        MMQ(0, 0);
        bf[2][0] = RD_B1(2, 0); bf[2][1] = RD_B1(2, 1);
        bf[3][0] = RD_B1(3, 0); bf[3][1] = RD_B1(3, 1);
        MMQ(0, 2);
#pragma unroll
        for (int i = 0; i < 4; ++i) {
            af[i][0] = RD_A1(4 + i, 0);
            af[i][1] = RD_A1(4 + i, 1);
        }
        MMQ(4, 0);
        MMQ(4, 2);
        __syncthreads();
    }

    if (MODE == 1 && vtg != nullptr && bN >= 2048) {  // QKV V-blocks: transposed to VtG
        int bb = bM >> 11;
#pragma unroll
        for (int i = 0; i < 8; ++i)
#pragma unroll
            for (int j = 0; j < 4; ++j) {
                int hd = bN - 2048 + wc * 64 + j * 16;
                int col = 2048 + hd + l15;
                int tb = (bM & 2047) + wr * 128 + i * 16 + quad * 4;
                _Float16* dst = (_Float16*)vtg +
                    (((size_t)(bb * 16 + (hd >> 6)) * 64) + (hd & 63) + l15) * TT + tb;
                f16x4 ov;
#pragma unroll
                for (int r = 0; r < 4; ++r) ov[r] = (_Float16)(acc[i][j][r] + bias[col]);
                *(f16x4*)dst = ov;
            }
        return;
    }

#pragma unroll
    for (int i = 0; i < 8; ++i)
#pragma unroll
        for (int j = 0; j < 4; ++j)
#pragma unroll
            for (int r = 0; r < 4; ++r) {
                int row = bM + wr * 128 + i * 16 + quad * 4 + r;
                int col = bN + wc * 64 + j * 16 + l15;
                size_t idx = (size_t)row * N + col;
                float vv = acc[i][j][r] + bias[col];
                if (MODE == 1) {
                    if (bN < 1024) vv *= SC2F;
                    ((_Float16*)outp)[idx] = (_Float16)vv;
                } else {  // MODE 0: FF1 gelu
                    ((_Float16*)outp)[idx] = (_Float16)gelu_fast(vv);
                }
            }
}

// ---------------- FF2: 128x128-tile K-split-2 2-phase GEMM, 256 thr, 2 blk/CU -------
// Flat grid 512 = 2 blocks/CU (64KB dbuf LDS): sibling block's MFMA covers this
// block's vmcnt(0) drain. XCD-aware mapping: xcd = bid&7; z-slice zz = xcd>>2 (4 XCDs
// per K-half), M-quarter mq = xcd&3, n-fastest within XCD -> per-XCD resident set =
// 4MB w2T z-slice + 512KB A-panel (reused across 8 consecutive n-blocks) ~ L2-fit.
// Partials (f16) -> p0/p1 at S0/S2 (attnout/x2, both dead; NO overlap with ff1 S4..S8
// or w2T S3 -- the R8 bug), summed by ff2_reduce.
__global__ __launch_bounds__(256) void gemm_ff2(const _Float16* __restrict__ A,
                                                const _Float16* __restrict__ Bt,
                                                _Float16* __restrict__ p0,
                                                _Float16* __restrict__ p1,
                                                int M, int N, int K, int lda, int ldb) {
    __shared__ _Float16 As[2][128][64];
    __shared__ _Float16 Bs[2][128][64];
    int tid = threadIdx.x;
    int lane = tid & 63, w = tid >> 6;   // w 0..3
    int quad = lane >> 4, l15 = lane & 15;
    int wr = (w >> 1) * 64, wc = (w & 1) * 64;  // 2x2 wave grid; per-wave 64x64
    int bid = blockIdx.x;                // 0..511
    int xcd = bid & 7;
    int j = bid >> 3;                    // 0..63
    int zz = xcd >> 2;                   // 0..1: K-half per XCD group
    int mq = xcd & 3;                    // M-quarter
    int n = j & 7;                       // n fastest: consecutive blocks share A-panel
    int m = (j >> 3) + mq * 8;           // 0..31
    int bM = m * 128, bN = n * 128;
    int kz = zz * 2048;
    int lr = lane >> 3;
    int lcs = ((lane & 7) ^ lr) * 8;
    int sw = l15 & 7;
    f32x4 acc[4][4] = {};
    f16x8 af[4][2], bf[4][2];

    const _Float16* Ab = A + (size_t)(bM + w * 32 + lr) * lda + kz + lcs;
    const _Float16* Bb = Bt + (size_t)(bN + w * 32 + lr) * ldb + kz + lcs;
    const int NT = 32;  // K=2048 per slice

#define FF2_STAGE(OB, TN)                                                                \
    {                                                                                    \
        size_t ko = (size_t)(TN) * 64;                                                   \
        _Pragma("unroll") for (int i = 0; i < 4; ++i) {                                  \
            __builtin_amdgcn_global_load_lds(                                            \
                (const __attribute__((address_space(1))) void*)(Ab + (size_t)(i * 8) * lda + ko), \
                (__attribute__((address_space(3))) void*)(&As[OB][w * 32 + i * 8][0]), 16, 0, 0); \
            __builtin_amdgcn_global_load_lds(                                            \
                (const __attribute__((address_space(1))) void*)(Bb + (size_t)(i * 8) * ldb + ko), \
                (__attribute__((address_space(3))) void*)(&Bs[OB][w * 32 + i * 8][0]), 16, 0, 0); \
        }                                                                                \
    }

    FF2_STAGE(0, 0);
    asm volatile("s_waitcnt vmcnt(0)" ::: "memory");
    __builtin_amdgcn_s_barrier();

    int cur = 0;
    for (int t = 0; t < NT; ++t) {
        int nxt = cur ^ 1;
        int tn = (t + 1 < NT) ? t + 1 : 0;  // last iter: dummy re-stage (never read)
        FF2_STAGE(nxt, tn);
#pragma unroll
        for (int i = 0; i < 4; ++i) {
#pragma unroll
            for (int ks = 0; ks < 2; ++ks)
                af[i][ks] = *(const f16x8*)(&As[cur][wr + i * 16 + l15][((ks * 4 + quad) ^ sw) * 8]);
        }
#pragma unroll
        for (int jj = 0; jj < 4; ++jj) {
#pragma unroll
            for (int ks = 0; ks < 2; ++ks)
                bf[jj][ks] = *(const f16x8*)(&Bs[cur][wc + jj * 16 + l15][((ks * 4 + quad) ^ sw) * 8]);
        }
#pragma unroll
        for (int ks = 0; ks < 2; ++ks)
#pragma unroll
            for (int i = 0; i < 4; ++i)
#pragma unroll
                for (int jj = 0; jj < 4; ++jj)
                    acc[i][jj] = __builtin_amdgcn_mfma_f32_16x16x32_f16(af[i][ks], bf[jj][ks], acc[i][jj], 0, 0, 0);
        asm volatile("s_waitcnt vmcnt(0)" ::: "memory");
        __builtin_amdgcn_s_barrier();
        cur = nxt;
    }

    _Float16* pout = zz ? p1 : p0;
#pragma unroll
    for (int i = 0; i < 4; ++i)
#pragma unroll
        for (int jj = 0; jj < 4; ++jj)
#pragma unroll
            for (int r = 0; r < 4; ++r) {
                int row = bM + wr + i * 16 + quad * 4 + r;
                int col = bN + wc + jj * 16 + l15;
                pout[(size_t)row * N + col] = (_Float16)acc[i][jj][r];
            }
}

// ---------------- GEMM 128Mx64N, single-buffer (R4 version), XOR swizzle ------------
// MODE 2: out f16 = resid(f32) + alpha*(acc+bias)          (attn proj -> xmid)
// MODE 4: out f32 = acc                                    (FF2 pass a, fallback)
// MODE 5: out f32 = resid(f16) + alpha*(out + acc + bias)  (FF2 pass b, fallback)
template <int MODE>
__global__ __launch_bounds__(256) void gemm64(const _Float16* __restrict__ A,
                                              const _Float16* __restrict__ Bt,
                                              const float* __restrict__ bias,
                                              void* __restrict__ outp,
                                              const void* __restrict__ residp,
                                              const float* __restrict__ alphap,
                                              int M, int N, int K, int lda, int ldb) {
    __shared__ _Float16 As[128][64];
    __shared__ _Float16 Bs[64][64];
    int tid = threadIdx.x;
    int lane = tid & 63, w = tid >> 6;
    int quad = lane >> 4, l15 = lane & 15;
    int wm = w * 32;
    int bM = blockIdx.y * 128, bN = blockIdx.x * 64;
    int lr = lane >> 3;
    int lcs = ((lane & 7) ^ lr) * 8;
    int sw = l15 & 7;
    f32x4 acc[2][4] = {};

    const _Float16* Abase = A + (size_t)(bM + w * 32 + lr) * lda + lcs;
    const _Float16* Bbase = Bt + (size_t)(bN + w * 16 + lr) * ldb + lcs;

    for (int kt = 0; kt < K; kt += 64) {
#pragma unroll
        for (int i = 0; i < 4; ++i)
            __builtin_amdgcn_global_load_lds(
                (const __attribute__((address_space(1))) void*)(Abase + (size_t)(i * 8) * lda + kt),
                (__attribute__((address_space(3))) void*)(&As[w * 32 + i * 8][0]), 16, 0, 0);
#pragma unroll
        for (int i = 0; i < 2; ++i)
            __builtin_amdgcn_global_load_lds(
                (const __attribute__((address_space(1))) void*)(Bbase + (size_t)(i * 8) * ldb + kt),
                (__attribute__((address_space(3))) void*)(&Bs[w * 16 + i * 8][0]), 16, 0, 0);
        __syncthreads();
#pragma unroll
        for (int ks = 0; ks < 2; ++ks) {
            int sc = ((ks * 4 + quad) ^ sw) * 8;
            f16x8 af[2], bf[4];
#pragma unroll
            for (int i = 0; i < 2; ++i)
                af[i] = *(const f16x8*)(&As[wm + i * 16 + l15][sc]);
#pragma unroll
            for (int j = 0; j < 4; ++j)
                bf[j] = *(const f16x8*)(&Bs[j * 16 + l15][sc]);
#pragma unroll
            for (int i = 0; i < 2; ++i)
#pragma unroll
                for (int j = 0; j < 4; ++j)
                    acc[i][j] = __builtin_amdgcn_mfma_f32_16x16x32_f16(af[i], bf[j], acc[i][j], 0, 0, 0);
        }
        __syncthreads();
    }

    float alpha = 0.f;
    if (MODE == 2 || MODE == 5) alpha = alphap[0];
#pragma unroll
    for (int i = 0; i < 2; ++i)
#pragma unroll
        for (int j = 0; j < 4; ++j)
#pragma unroll
            for (int r = 0; r < 4; ++r) {
                int row = bM + wm + i * 16 + quad * 4 + r;
                int col = bN + j * 16 + l15;
                size_t idx = (size_t)row * N + col;
                if (MODE == 4) {
                    ((float*)outp)[idx] = acc[i][j][r];
                } else if (MODE == 2) {
                    float vv = acc[i][j][r] + bias[col];
                    float rsd = ((const float*)residp)[idx];
                    ((_Float16*)outp)[idx] = (_Float16)(rsd + alpha * vv);
                } else {  // MODE 5
                    float vv = acc[i][j][r] + bias[col];
                    float prev = ((float*)outp)[idx];
                    float rsd = (float)((const _Float16*)residp)[idx];
                    ((float*)outp)[idx] = rsd + alpha * (prev + vv);
                }
            }
}

// ---------------- FF2 reduce: d_out = xmid + alpha*(p0+p1+b2), vectorized x8 --------
__global__ __launch_bounds__(256) void ff2_reduce_kernel(const _Float16* __restrict__ p0,
                                                         const _Float16* __restrict__ p1,
                                                         const _Float16* __restrict__ xmid,
                                                         const float* __restrict__ b2,
                                                         const float* __restrict__ alphap,
                                                         float* __restrict__ out) {
    int i = (blockIdx.x * 256 + threadIdx.x) * 8;
    float alpha = alphap[0];
    f16x8 a = *(const f16x8*)(p0 + i);
    f16x8 b = *(const f16x8*)(p1 + i);
    f16x8 xm = *(const f16x8*)(xmid + i);
    int col = i & 1023;
#pragma unroll
    for (int k = 0; k < 8; ++k)
        out[i + k] = (float)xm[k] + alpha * ((float)a[k] + (float)b[k] + b2[col + k]);
}

// ---------------- MFMA flash attention: balanced 8-wave, 2 q-tiles/block ------------
#define QT 64
#define NEG_BIG (-1e30f)
__global__ __launch_bounds__(512) void attn_mfma_kernel(const _Float16* __restrict__ qkv,
                                                        const _Float16* __restrict__ VtG,
                                                        _Float16* __restrict__ O) {
    __shared__ _Float16 Ks[64][72];
    __shared__ _Float16 Vt[64][72];
    __shared__ _Float16 Ps[8][16][68];
    int tid = threadIdx.x;
    int lane = tid & 63, w = tid >> 6;     // w in 0..7
    int quad = lane >> 4, l15 = lane & 15;
    int bh = blockIdx.x;
    int b = bh >> 4, h = bh & 15;
    int y = blockIdx.y;                    // 0..15
    int seg = w >> 2, ws = w & 3;          // seg 0: long q-tile, seg 1: short
    int qt = seg ? y : (31 - y);
    int q0 = qt * QT;
    int ntw = qt + 1;                      // K-tiles THIS wave computes
    int ntmax = 32 - y;                    // K-tiles staged (= long wave's ntw)
    const _Float16* Qh = qkv + (size_t)b * TT * QKVS + h * HD;
    const _Float16* Kh = Qh + 1024;
    const _Float16* Vrows = VtG + (size_t)bh * HD * TT;

    int m0 = q0 + ws * 16;
    f16x8 aq0 = *(const f16x8*)(Qh + (size_t)(m0 + l15) * QKVS + quad * 8);
    f16x8 aq1 = *(const f16x8*)(Qh + (size_t)(m0 + l15) * QKVS + 32 + quad * 8);

    f32x4 Oacc[4] = {};
    float lrow[4] = {0.f, 0.f, 0.f, 0.f};

    // staging: 512 threads cover 64 rows x 64 cols, one f16x8 each per buffer
    int rr = tid >> 3;                     // 0..63
    int c8 = (tid & 7) * 8;
    const _Float16* Kp = Kh + (size_t)rr * QKVS + c8;
    const _Float16* Vp = Vrows + (size_t)rr * TT + c8;

    f16x8 kreg = *(const f16x8*)(Kp);
    f16x8 vreg = *(const f16x8*)(Vp);

    for (int t = 0; t < ntmax; ++t) {
        int t0 = t * 64;
        __syncthreads();
        *(f16x8*)(&Ks[rr][c8]) = kreg;
        *(f16x8*)(&Vt[rr][c8]) = vreg;
        __syncthreads();
        if (t + 1 < ntmax) {
            kreg = *(const f16x8*)(Kp + (size_t)(t0 + 64) * QKVS);
            vreg = *(const f16x8*)(Vp + t0 + 64);
        }
        if (t >= ntw) continue;           // short-seg waves: stage+barrier only

        f32x4 Sacc[4] = {};
        __builtin_amdgcn_s_setprio(1);
#pragma unroll
        for (int nc = 0; nc < 4; ++nc) {
            f16x8 bk0 = *(const f16x8*)(&Ks[nc * 16 + l15][quad * 8]);
            f16x8 bk1 = *(const f16x8*)(&Ks[nc * 16 + l15][32 + quad * 8]);
            Sacc[nc] = __builtin_amdgcn_mfma_f32_16x16x32_f16(aq0, bk0, Sacc[nc], 0, 0, 0);
            Sacc[nc] = __builtin_amdgcn_mfma_f32_16x16x32_f16(aq1, bk1, Sacc[nc], 0, 0, 0);
        }
        __builtin_amdgcn_s_setprio(0);

        if (t0 == q0) {  // diagonal tile: causal mask
#pragma unroll
            for (int nc = 0; nc < 4; ++nc) {
                int key = t0 + nc * 16 + l15;
#pragma unroll
                for (int i = 0; i < 4; ++i)
                    if (key > m0 + quad * 4 + i) Sacc[nc][i] = NEG_BIG;
            }
        }

        // P = exp2(S) (no max subtraction), accumulate per-lane l
#pragma unroll
        for (int nc = 0; nc < 4; ++nc)
#pragma unroll
            for (int i = 0; i < 4; ++i) {
                float p = exp2f(Sacc[nc][i]);
                lrow[i] += p;
                Ps[w][quad * 4 + i][nc * 16 + l15] = (_Float16)p;
            }
        __asm__ __volatile__("s_waitcnt lgkmcnt(0)" ::: "memory");  // wave-local roundtrip

        f16x8 ap0 = *(const f16x8*)(&Ps[w][l15][quad * 8]);
        f16x8 ap1 = *(const f16x8*)(&Ps[w][l15][32 + quad * 8]);
        __builtin_amdgcn_s_setprio(1);
#pragma unroll
        for (int nc = 0; nc < 4; ++nc) {
            int d = nc * 16 + l15;
            f16x8 bv0 = *(const f16x8*)(&Vt[d][quad * 8]);
            f16x8 bv1 = *(const f16x8*)(&Vt[d][32 + quad * 8]);
            Oacc[nc] = __builtin_amdgcn_mfma_f32_16x16x32_f16(ap0, bv0, Oacc[nc], 0, 0, 0);
            Oacc[nc] = __builtin_amdgcn_mfma_f32_16x16x32_f16(ap1, bv1, Oacc[nc], 0, 0, 0);
        }
        __builtin_amdgcn_s_setprio(0);
    }

#pragma unroll
    for (int off = 1; off < 16; off <<= 1)
#pragma unroll
        for (int i = 0; i < 4; ++i) lrow[i] += __shfl_xor(lrow[i], off);
#pragma unroll
    for (int i = 0; i < 4; ++i) lrow[i] = 1.0f / lrow[i];
    _Float16* Oh = O + (size_t)b * TT * EMB + h * HD;
#pragma unroll
    for (int nc = 0; nc < 4; ++nc)
#pragma unroll
        for (int i = 0; i < 4; ++i) {
            int row = m0 + quad * 4 + i;
            Oh[(size_t)row * EMB + nc * 16 + l15] = (_Float16)(Oacc[nc][i] * lrow[i]);
        }
}

extern "C" void kernel_launch(void* const* d_in, const int* in_sizes, int n_in,
                              void* d_out, int out_size, void* d_ws, size_t ws_size,
                              hipStream_t stream) {
    const float* x = (const float*)d_in[0];
    const float* wq = (const float*)d_in[1];
    const float* bq = (const float*)d_in[2];
    const float* wk = (const float*)d_in[3];
    const float* bk = (const float*)d_in[4];
    const float* wv = (const float*)d_in[5];
    const float* bv = (const float*)d_in[6];
    const float* wo = (const float*)d_in[7];
    const float* bo = (const float*)d_in[8];
    const float* w1 = (const float*)d_in[9];
    const float* b1 = (const float*)d_in[10];
    const float* w2 = (const float*)d_in[11];
    const float* b2 = (const float*)d_in[12];
    const float* ln1_g = (const float*)d_in[13];
    const float* ln1_b = (const float*)d_in[14];
    const float* ln2_g = (const float*)d_in[15];
    const float* ln2_b = (const float*)d_in[16];
    const float* alpha_attn = (const float*)d_in[17];
    const float* alpha_ff = (const float*)d_in[18];

    const size_t SL = (size_t)8 * 1024 * 1024;
    char* ws = (char*)d_ws;
    _Float16* xn = (_Float16*)(ws);
    _Float16* qkv = (_Float16*)(ws + SL);
    _Float16* wqkvT = (_Float16*)(ws + 4 * SL);
    float* qkvbias = (float*)(ws + 4 * SL + 6 * 1024 * 1024);
    _Float16* attnout = (_Float16*)(ws);
    _Float16* xmid = (_Float16*)(ws + SL);
    _Float16* x2 = (_Float16*)(ws + 2 * SL);
    _Float16* w1T = (_Float16*)(ws);
    _Float16* w2T = (_Float16*)(ws + 3 * SL);
    _Float16* ff1 = (_Float16*)(ws + 4 * SL);
    bool bigws = ws_size >= (size_t)64 * 1024 * 1024;
    // bigws: VtG=S5, woT=S6 (no aliasing with wqkvT during QKV, fused vT OK).
    // fallback (48MB): VtG=S4 (overwrites wqkvT AFTER QKV via separate vT kernel),
    //                  woT=S5; fused vT disabled (would alias wqkvT mid-GEMM).
    _Float16* VtG = bigws ? (_Float16*)(ws + 5 * SL) : (_Float16*)(ws + 4 * SL);
    _Float16* woT = bigws ? (_Float16*)(ws + 6 * SL) : (_Float16*)(ws + 5 * SL);
    // FF2 partials: S0 (attnout dead) and S2 (x2 dead after FF1). Do NOT use S5/S6:
    // ff1 is 32MB spanning S4..S8 and is gemm_ff2's live A operand (R8 bug).
    _Float16* part0 = (_Float16*)(ws);
    _Float16* part1 = (_Float16*)(ws + 2 * SL);

    prep0_kernel<<<8204, 256, 0, stream>>>(x, xn, ln1_g, ln1_b, wq, wk, wv, wo,
                                           bq, bk, bv, wqkvT, woT, qkvbias);

    if (bigws) {
        gemm256<1><<<dim3(QKVS / 256, NTOK / 256), 512, 0, stream>>>(
            xn, wqkvT, qkvbias, qkv, (void*)VtG, NTOK, QKVS, EMB, EMB, EMB);
    } else {
        gemm_f16t<6><<<dim3(QKVS / 128, NTOK / 128), 256, 0, stream>>>(
            xn, wqkvT, qkvbias, qkv, nullptr, NTOK, QKVS, EMB, EMB, EMB);
        vT_kernel<<<dim3(TT / 64, BB * NH), 256, 0, stream>>>(qkv, VtG);
    }

    attn_mfma_kernel<<<dim3(BB * NH, TT / QT / 2), 512, 0, stream>>>(qkv, VtG, attnout);

    gemm64<2><<<dim3(EMB / 64, NTOK / 128), 256, 0, stream>>>(
        attnout, woT, bo, xmid, x, alpha_attn, NTOK, EMB, EMB, EMB, EMB);

    ln_kernel<_Float16><<<NTOK, 256, 0, stream>>>(xmid, x2, ln2_g, ln2_b);

    prep2_kernel<<<8192, 256, 0, stream>>>(w1, w2, w1T, w2T);

    if (bigws) {
        gemm256<0><<<dim3(FF_DIM / 256, NTOK / 256), 512, 0, stream>>>(
            x2, w1T, b1, ff1, nullptr, NTOK, FF_DIM, EMB, EMB, EMB);
        gemm_ff2<<<512, 256, 0, stream>>>(
            ff1, w2T, part0, part1, NTOK, EMB, FF_DIM, FF_DIM, FF_DIM);
        ff2_reduce_kernel<<<NTOK * EMB / 8 / 256, 256, 0, stream>>>(
            part0, part1, xmid, b2, alpha_ff, (float*)d_out);
    } else {
        const int NC = 2048;
        for (int hh = 0; hh < 2; ++hh) {
            const _Float16* w1Th = w1T + (size_t)hh * NC * EMB;
            const _Float16* w2Th = w2T + (size_t)hh * NC;
            gemm_f16t<1><<<dim3(NC / 128, NTOK / 128), 256, 0, stream>>>(
                x2, w1Th, b1 + hh * NC, ff1, nullptr, NTOK, NC, EMB, EMB, EMB);
            if (hh == 0)
                gemm64<4><<<dim3(EMB / 64, NTOK / 128), 256, 0, stream>>>(
                    ff1, w2Th, nullptr, d_out, nullptr, nullptr, NTOK, EMB, NC, NC, FF_DIM);
            else
                gemm64<5><<<dim3(EMB / 64, NTOK / 128), 256, 0, stream>>>(
                    ff1, w2Th, b2, d_out, xmid, alpha_ff, NTOK, EMB, NC, NC, FF_DIM);
        }
    }
}

// Round 13
// 323.356 us; speedup vs baseline: 1.0788x; 1.0450x over previous
//
#include <hip/hip_runtime.h>
#include <cmath>

#define EMB 1024
#define NH 16
#define HD 64
#define FF_DIM 4096
#define BB 2
#define TT 2048
#define NTOK (BB * TT)
#define QKVS 3072
#define SC2F 0.18033688011112042f  // log2(e) / sqrt(64), folded into Q at QKV epilogue

typedef _Float16 f16x8 __attribute__((ext_vector_type(8)));
typedef _Float16 f16x4 __attribute__((ext_vector_type(4)));
typedef float f32x4 __attribute__((ext_vector_type(4)));

// fast tanh-GELU, NaN-safe: x*e/(e+1) written as x - x/(e+1)
__device__ __forceinline__ float gelu_fast(float x) {
    float u = x * (1.f + 0.044715f * x * x);
    float e = exp2f(u * 2.302118751f);  // 2 * 0.7978845608 * log2(e)
    return x - x / (e + 1.f);
}

// ---------------- LayerNorm: one block (256 thr) per token, EMB=1024 ----------------
template <typename TIN>
__global__ __launch_bounds__(256) void ln_kernel(const TIN* __restrict__ xin,
                                                 _Float16* __restrict__ out,
                                                 const float* __restrict__ g,
                                                 const float* __restrict__ bv) {
    int tid = threadIdx.x;
    size_t base = (size_t)blockIdx.x * EMB;
    float v[4];
#pragma unroll
    for (int i = 0; i < 4; ++i) v[i] = (float)xin[base + i * 256 + tid];
    float s = v[0] + v[1] + v[2] + v[3];
    float ss = v[0] * v[0] + v[1] * v[1] + v[2] * v[2] + v[3] * v[3];
#pragma unroll
    for (int off = 32; off > 0; off >>= 1) {
        s += __shfl_down(s, off);
        ss += __shfl_down(ss, off);
    }
    __shared__ float red[8];
    int wave = tid >> 6;
    if ((tid & 63) == 0) { red[wave] = s; red[4 + wave] = ss; }
    __syncthreads();
    s = red[0] + red[1] + red[2] + red[3];
    ss = red[4] + red[5] + red[6] + red[7];
    float mu = s * (1.0f / EMB);
    float var = ss * (1.0f / EMB) - mu * mu;
    float rstd = rsqrtf(var + 1e-5f);
#pragma unroll
    for (int i = 0; i < 4; ++i) {
        int idx = i * 256 + tid;
        float y = (v[i] - mu) * rstd * g[idx] + bv[idx];
        out[base + idx] = (_Float16)y;
    }
}

// ---------------- fused: LN1 + wq/wk/wv/wo cast+transpose + qkv bias ----------------
// grid 8204: [0,4096) weight tiles, [4096,4108) bias, [4108,8204) LN1 tokens
__global__ __launch_bounds__(256) void prep0_kernel(const float* __restrict__ x,
                                                    _Float16* __restrict__ xn,
                                                    const float* __restrict__ ln1_g,
                                                    const float* __restrict__ ln1_b,
                                                    const float* __restrict__ wq,
                                                    const float* __restrict__ wk,
                                                    const float* __restrict__ wv,
                                                    const float* __restrict__ wo,
                                                    const float* __restrict__ bq,
                                                    const float* __restrict__ bk,
                                                    const float* __restrict__ bv,
                                                    _Float16* __restrict__ wqkvT,
                                                    _Float16* __restrict__ woT,
                                                    float* __restrict__ qkvbias) {
    __shared__ float tile[32][33];
    int blk = blockIdx.x;
    int tid = threadIdx.x;
    if (blk >= 4108) {  // ---- LN1 ----
        size_t base = (size_t)(blk - 4108) * EMB;
        float v[4];
#pragma unroll
        for (int i = 0; i < 4; ++i) v[i] = x[base + i * 256 + tid];
        float s = v[0] + v[1] + v[2] + v[3];
        float ss = v[0] * v[0] + v[1] * v[1] + v[2] * v[2] + v[3] * v[3];
#pragma unroll
        for (int off = 32; off > 0; off >>= 1) {
            s += __shfl_down(s, off);
            ss += __shfl_down(ss, off);
        }
        float* red = &tile[0][0];
        int wave = tid >> 6;
        if ((tid & 63) == 0) { red[wave] = s; red[4 + wave] = ss; }
        __syncthreads();
        s = red[0] + red[1] + red[2] + red[3];
        ss = red[4] + red[5] + red[6] + red[7];
        float mu = s * (1.0f / EMB);
        float var = ss * (1.0f / EMB) - mu * mu;
        float rstd = rsqrtf(var + 1e-5f);
#pragma unroll
        for (int i = 0; i < 4; ++i) {
            int idx = i * 256 + tid;
            xn[base + idx] = (_Float16)((v[i] - mu) * rstd * ln1_g[idx] + ln1_b[idx]);
        }
        return;
    }
    if (blk >= 4096) {  // ---- fused qkv bias ----
        int i = (blk - 4096) * 256 + tid;  // 0..3071
        qkvbias[i] = i < 1024 ? bq[i] : (i < 2048 ? bk[i - 1024] : bv[i - 2048]);
        return;
    }
    // ---- weight cast+transpose ----
    const float* W;
    _Float16* Wt;
    int t = blk & 1023;
    int z = blk >> 10;
    if (z == 0) { W = wq; Wt = wqkvT; }
    else if (z == 1) { W = wk; Wt = wqkvT + 1024 * 1024; }
    else if (z == 2) { W = wv; Wt = wqkvT + 2 * 1024 * 1024; }
    else { W = wo; Wt = woT; }
    int bx = (t & 31) * 32, by = (t >> 5) * 32;
    int tx = tid & 31, ty = tid >> 5;
#pragma unroll
    for (int i = 0; i < 32; i += 8)
        tile[ty + i][tx] = W[(size_t)(by + ty + i) * EMB + bx + tx];
    __syncthreads();
#pragma unroll
    for (int i = 0; i < 32; i += 8)
        Wt[(size_t)(bx + ty + i) * EMB + by + tx] = (_Float16)tile[tx][ty + i];
}

// ---------------- merged LN2 + prep2 (w1/w2 cast+transpose): one launch -------------
// grid 12288: [0,4096) w1 tiles, [4096,8192) w2 tiles, [8192,12288) LN2 tokens
__global__ __launch_bounds__(256) void lnprep2_kernel(const _Float16* __restrict__ xmid,
                                                      _Float16* __restrict__ x2,
                                                      const float* __restrict__ ln2_g,
                                                      const float* __restrict__ ln2_b,
                                                      const float* __restrict__ w1,
                                                      const float* __restrict__ w2,
                                                      _Float16* __restrict__ w1T,
                                                      _Float16* __restrict__ w2T) {
    __shared__ float tile[32][33];
    int blk = blockIdx.x;
    int tid = threadIdx.x;
    if (blk >= 8192) {  // ---- LN2 ----
        size_t base = (size_t)(blk - 8192) * EMB;
        float v[4];
#pragma unroll
        for (int i = 0; i < 4; ++i) v[i] = (float)xmid[base + i * 256 + tid];
        float s = v[0] + v[1] + v[2] + v[3];
        float ss = v[0] * v[0] + v[1] * v[1] + v[2] * v[2] + v[3] * v[3];
#pragma unroll
        for (int off = 32; off > 0; off >>= 1) {
            s += __shfl_down(s, off);
            ss += __shfl_down(ss, off);
        }
        float* red = &tile[0][0];
        int wave = tid >> 6;
        if ((tid & 63) == 0) { red[wave] = s; red[4 + wave] = ss; }
        __syncthreads();
        s = red[0] + red[1] + red[2] + red[3];
        ss = red[4] + red[5] + red[6] + red[7];
        float mu = s * (1.0f / EMB);
        float var = ss * (1.0f / EMB) - mu * mu;
        float rstd = rsqrtf(var + 1e-5f);
#pragma unroll
        for (int i = 0; i < 4; ++i) {
            int idx = i * 256 + tid;
            x2[base + idx] = (_Float16)((v[i] - mu) * rstd * ln2_g[idx] + ln2_b[idx]);
        }
        return;
    }
    // ---- w1 / w2 cast+transpose ----
    const float* W;
    _Float16* Wt;
    int K, N, t;
    if (blk < 4096) { W = w1; Wt = w1T; K = 1024; N = 4096; t = blk; }
    else { W = w2; Wt = w2T; K = 4096; N = 1024; t = blk - 4096; }
    int ntx = N >> 5;
    int bx = (t % ntx) * 32, by = (t / ntx) * 32;
    int tx = tid & 31, ty = tid >> 5;
#pragma unroll
    for (int i = 0; i < 32; i += 8)
        tile[ty + i][tx] = W[(size_t)(by + ty + i) * N + bx + tx];
    __syncthreads();
#pragma unroll
    for (int i = 0; i < 32; i += 8)
        Wt[(size_t)(bx + ty + i) * K + by + tx] = (_Float16)tile[tx][ty + i];
}

// ---------------- V transpose (48MB-fallback only) ----------------------------------
__global__ __launch_bounds__(256) void vT_kernel(const _Float16* __restrict__ qkv,
                                                 _Float16* __restrict__ VtG) {
    __shared__ _Float16 tile[64][72];
    int tid = threadIdx.x;
    int bh = blockIdx.y;
    int b = bh >> 4, h = bh & 15;
    int t0 = blockIdx.x * 64;
    const _Float16* src = qkv + (size_t)b * TT * QKVS + 2048 + h * HD;
    int r = tid >> 3;
    int c8 = (tid & 7) * 8;
#pragma unroll
    for (int p = 0; p < 2; ++p)
        *(f16x8*)(&tile[r + p * 32][c8]) =
            *(const f16x8*)(src + (size_t)(t0 + r + p * 32) * QKVS + c8);
    __syncthreads();
#pragma unroll
    for (int p = 0; p < 2; ++p) {
        int d = r + p * 32;
        f16x8 v;
#pragma unroll
        for (int j = 0; j < 8; ++j) v[j] = tile[c8 + j][d];
        *(f16x8*)(VtG + ((size_t)bh * HD + d) * TT + t0 + c8) = v;
    }
}

// ---------------- m97-style GEMM 128x128 with XOR-swizzled LDS ----------------------
// MODE 6: QKV fused (Q scaled by SC2F; V blocks written transposed to VtG if vtg)
// MODE 1: out f16 = gelu_fast(acc+bias)                  (FF1)  [fallback path only]
template <int MODE>
__global__ __launch_bounds__(256) void gemm_f16t(const _Float16* __restrict__ A,
                                                 const _Float16* __restrict__ Bt,
                                                 const float* __restrict__ bias,
                                                 void* __restrict__ outp,
                                                 void* __restrict__ vtg,
                                                 int M, int N, int K, int lda, int ldb) {
    __shared__ _Float16 As[128][64];  // NO padding: global_load_lds lane ordering
    __shared__ _Float16 Bs[128][64];
    int tid = threadIdx.x;
    int lane = tid & 63, w = tid >> 6;
    int quad = lane >> 4, l15 = lane & 15;
    int wm = (w >> 1) * 64, wn = (w & 1) * 64;
    int bM = blockIdx.y * 128, bN = blockIdx.x * 128;
    int lr = lane >> 3;
    int lcs = ((lane & 7) ^ lr) * 8;  // swizzled source k-chunk
    int sw = l15 & 7;
    f32x4 acc[4][4] = {};

    const _Float16* Abase = A + (size_t)(bM + w * 32 + lr) * lda + lcs;
    const _Float16* Bbase = Bt + (size_t)(bN + w * 32 + lr) * ldb + lcs;

    for (int kt = 0; kt < K; kt += 64) {
#pragma unroll
        for (int i = 0; i < 4; ++i) {
            __builtin_amdgcn_global_load_lds(
                (const __attribute__((address_space(1))) void*)(Abase + (size_t)(i * 8) * lda + kt),
                (__attribute__((address_space(3))) void*)(&As[w * 32 + i * 8][0]), 16, 0, 0);
            __builtin_amdgcn_global_load_lds(
                (const __attribute__((address_space(1))) void*)(Bbase + (size_t)(i * 8) * ldb + kt),
                (__attribute__((address_space(3))) void*)(&Bs[w * 32 + i * 8][0]), 16, 0, 0);
        }
        __syncthreads();
#pragma unroll
        for (int ks = 0; ks < 2; ++ks) {
            f16x8 af[4], bf[4];
#pragma unroll
            for (int i = 0; i < 4; ++i) {
                int sc = ((ks * 4 + quad) ^ sw) * 8;
                af[i] = *(const f16x8*)(&As[wm + i * 16 + l15][sc]);
                bf[i] = *(const f16x8*)(&Bs[wn + i * 16 + l15][sc]);
            }
#pragma unroll
            for (int i = 0; i < 4; ++i)
#pragma unroll
                for (int j = 0; j < 4; ++j)
                    acc[i][j] = __builtin_amdgcn_mfma_f32_16x16x32_f16(af[i], bf[j], acc[i][j], 0, 0, 0);
        }
        __syncthreads();
    }

    if (MODE == 6 && vtg != nullptr && bN >= 2048) {
        int bb = bM >> 11;
        int tbase = (bM & 2047) + wm;
#pragma unroll
        for (int i = 0; i < 4; ++i)
#pragma unroll
            for (int j = 0; j < 4; ++j) {
                int hd = bN - 2048 + wn + j * 16;
                int col = 2048 + hd + l15;
                _Float16* dst = (_Float16*)vtg +
                    (((size_t)(bb * 16 + (hd >> 6)) * 64) + (hd & 63) + l15) * TT +
                    tbase + i * 16 + quad * 4;
                f16x4 ov;
#pragma unroll
                for (int r = 0; r < 4; ++r) ov[r] = (_Float16)(acc[i][j][r] + bias[col]);
                *(f16x4*)dst = ov;
            }
        return;
    }

#pragma unroll
    for (int i = 0; i < 4; ++i)
#pragma unroll
        for (int j = 0; j < 4; ++j)
#pragma unroll
            for (int r = 0; r < 4; ++r) {
                int row = bM + wm + i * 16 + quad * 4 + r;
                int col = bN + wn + j * 16 + l15;
                size_t idx = (size_t)row * N + col;
                float vv = acc[i][j][r] + bias[col];
                if (MODE == 6) {
                    if (bN < 1024) vv *= SC2F;
                    ((_Float16*)outp)[idx] = (_Float16)vv;
                } else {  // MODE 1
                    ((_Float16*)outp)[idx] = (_Float16)gelu_fast(vv);
                }
            }
}

// ---------------- 256x256 2-phase GEMM (R9 version, best measured), 512 thr ---------
// Per K-tile: {STAGE next tile (8 global_load_lds) -> interleaved ds_read/MFMA over
// current buffer (NO intra-tile barriers) -> vmcnt(0) -> ONE s_barrier}.
// MODE 0: out f16 = gelu_fast(acc+bias)                          (FF1)
// MODE 1: QKV fused epilogue (Q scale, V->VtG transposed, bias)   (QKV)
#define STAGE_PAIR(OB, TN, I)                                                            \
    {                                                                                    \
        size_t ko = (size_t)(TN) * 64;                                                   \
        __builtin_amdgcn_global_load_lds(                                                \
            (const __attribute__((address_space(1))) void*)(Ab + (size_t)((I) * 8) * lda + ko), \
            (__attribute__((address_space(3))) void*)(&As[OB][w * 32 + (I) * 8][0]), 16, 0, 0); \
        __builtin_amdgcn_global_load_lds(                                                \
            (const __attribute__((address_space(1))) void*)(Bb + (size_t)((I) * 8) * ldb + ko), \
            (__attribute__((address_space(3))) void*)(&Bs[OB][w * 32 + (I) * 8][0]), 16, 0, 0); \
    }
#define RD_A(CB, I, KS) (*(const f16x8*)(&As[CB][wr * 128 + (I) * 16 + l15][(((KS)*4 + quad) ^ sw) * 8]))
#define RD_B(CB, J, KS) (*(const f16x8*)(&Bs[CB][wc * 64 + (J) * 16 + l15][(((KS)*4 + quad) ^ sw) * 8]))
#define MMQ(I0, J0)                                                                      \
    _Pragma("unroll") for (int ks = 0; ks < 2; ++ks) {                                   \
        _Pragma("unroll") for (int ii = 0; ii < 4; ++ii) {                               \
            _Pragma("unroll") for (int jj = 0; jj < 2; ++jj)                             \
                acc[(I0) + ii][(J0) + jj] = __builtin_amdgcn_mfma_f32_16x16x32_f16(      \
                    af[ii][ks], bf[(J0) + jj][ks], acc[(I0) + ii][(J0) + jj], 0, 0, 0);  \
        }                                                                                \
    }

template <int MODE>
__global__ __launch_bounds__(512, 2) void gemm256(const _Float16* __restrict__ A,
                                                  const _Float16* __restrict__ Bt,
                                                  const float* __restrict__ bias,
                                                  void* __restrict__ outp,
                                                  void* __restrict__ vtg,
                                                  int M, int N, int K, int lda, int ldb) {
    __shared__ _Float16 As[2][256][64];
    __shared__ _Float16 Bs[2][256][64];
    int tid = threadIdx.x;
    int lane = tid & 63, w = tid >> 6;   // w 0..7
    int quad = lane >> 4, l15 = lane & 15;
    int wr = w >> 2, wc = w & 3;         // 2x4 wave grid; per-wave out 128x64
    // XCD-bijective block swizzle (grid size divisible by 8 for our shapes)
    int gx = gridDim.x;
    int nwg = gx * gridDim.y;
    int bid = blockIdx.y * gx + blockIdx.x;
    int cpx = nwg >> 3;
    int sbid = (bid & 7) * cpx + (bid >> 3);
    int bN = (sbid % gx) * 256;
    int bM = (sbid / gx) * 256;
    int lr = lane >> 3;
    int lcs = ((lane & 7) ^ lr) * 8;     // swizzled source k-chunk
    int sw = l15 & 7;
    f32x4 acc[8][4] = {};
    f16x8 af[4][2], bf[4][2];

    const _Float16* Ab = A + (size_t)(bM + w * 32 + lr) * lda + lcs;
    const _Float16* Bb = Bt + (size_t)(bN + w * 32 + lr) * ldb + lcs;
    const int NT = K >> 6;  // K-tiles (16 for K=1024)

    // prologue: stage tile 0 -> buf0, drain, sync
#pragma unroll
    for (int i = 0; i < 4; ++i) STAGE_PAIR(0, 0, i);
    asm volatile("s_waitcnt vmcnt(0)" ::: "memory");
    __builtin_amdgcn_s_barrier();

    int cur = 0;
    for (int t = 0; t < NT; ++t) {
        int nxt = cur ^ 1;
        int tn = (t + 1 < NT) ? t + 1 : 0;  // last iter: dummy re-stage of tile 0 (never read)
#pragma unroll
        for (int i = 0; i < 4; ++i) STAGE_PAIR(nxt, tn, i);
#pragma unroll
        for (int i = 0; i < 4; ++i) {
            af[i][0] = RD_A(cur, i, 0);
            af[i][1] = RD_A(cur, i, 1);
        }
        bf[0][0] = RD_B(cur, 0, 0); bf[0][1] = RD_B(cur, 0, 1);
        bf[1][0] = RD_B(cur, 1, 0); bf[1][1] = RD_B(cur, 1, 1);
        MMQ(0, 0);
        bf[2][0] = RD_B(cur, 2, 0); bf[2][1] = RD_B(cur, 2, 1);
        bf[3][0] = RD_B(cur, 3, 0); bf[3][1] = RD_B(cur, 3, 1);
        MMQ(0, 2);
#pragma unroll
        for (int i = 0; i < 4; ++i) {
            af[i][0] = RD_A(cur, 4 + i, 0);
            af[i][1] = RD_A(cur, 4 + i, 1);
        }
        MMQ(4, 0);
        MMQ(4, 2);
        asm volatile("s_waitcnt vmcnt(0)" ::: "memory");
        __builtin_amdgcn_s_barrier();
        cur = nxt;
    }

    if (MODE == 1 && vtg != nullptr && bN >= 2048) {  // QKV V-blocks: transposed to VtG
        int bb = bM >> 11;
#pragma unroll
        for (int i = 0; i < 8; ++i)
#pragma unroll
            for (int j = 0; j < 4; ++j) {
                int hd = bN - 2048 + wc * 64 + j * 16;
                int col = 2048 + hd + l15;
                int tb = (bM & 2047) + wr * 128 + i * 16 + quad * 4;
                _Float16* dst = (_Float16*)vtg +
                    (((size_t)(bb * 16 + (hd >> 6)) * 64) + (hd & 63) + l15) * TT + tb;
                f16x4 ov;
#pragma unroll
                for (int r = 0; r < 4; ++r) ov[r] = (_Float16)(acc[i][j][r] + bias[col]);
                *(f16x4*)dst = ov;
            }
        return;
    }

#pragma unroll
    for (int i = 0; i < 8; ++i)
#pragma unroll
        for (int j = 0; j < 4; ++j)
#pragma unroll
            for (int r = 0; r < 4; ++r) {
                int row = bM + wr * 128 + i * 16 + quad * 4 + r;
                int col = bN + wc * 64 + j * 16 + l15;
                size_t idx = (size_t)row * N + col;
                float vv = acc[i][j][r] + bias[col];
                if (MODE == 1) {
                    if (bN < 1024) vv *= SC2F;
                    ((_Float16*)outp)[idx] = (_Float16)vv;
                } else {  // MODE 0: FF1 gelu
                    ((_Float16*)outp)[idx] = (_Float16)gelu_fast(vv);
                }
            }
}

// ---------------- FF2: 128x128-tile K-split-2 2-phase GEMM, 256 thr, 2 blk/CU -------
// Flat grid 512 = 2 blocks/CU (64KB dbuf LDS): sibling block's MFMA covers this
// block's vmcnt(0) drain. XCD-aware mapping: xcd = bid&7; z-slice zz = xcd>>2 (4 XCDs
// per K-half), M-quarter mq = xcd&3, n-fastest within XCD -> per-XCD resident set =
// 4MB w2T z-slice + 512KB A-panel (reused across 8 consecutive n-blocks) ~ L2-fit.
// Partials (f16) -> p0/p1 at S0/S2 (attnout/x2, both dead; NO overlap with ff1 S4..S8
// or w2T S3 -- the R8 bug), summed by ff2_reduce.
__global__ __launch_bounds__(256) void gemm_ff2(const _Float16* __restrict__ A,
                                                const _Float16* __restrict__ Bt,
                                                _Float16* __restrict__ p0,
                                                _Float16* __restrict__ p1,
                                                int M, int N, int K, int lda, int ldb) {
    __shared__ _Float16 As[2][128][64];
    __shared__ _Float16 Bs[2][128][64];
    int tid = threadIdx.x;
    int lane = tid & 63, w = tid >> 6;   // w 0..3
    int quad = lane >> 4, l15 = lane & 15;
    int wr = (w >> 1) * 64, wc = (w & 1) * 64;  // 2x2 wave grid; per-wave 64x64
    int bid = blockIdx.x;                // 0..511
    int xcd = bid & 7;
    int j = bid >> 3;                    // 0..63
    int zz = xcd >> 2;                   // 0..1: K-half per XCD group
    int mq = xcd & 3;                    // M-quarter
    int n = j & 7;                       // n fastest: consecutive blocks share A-panel
    int m = (j >> 3) + mq * 8;           // 0..31
    int bM = m * 128, bN = n * 128;
    int kz = zz * 2048;
    int lr = lane >> 3;
    int lcs = ((lane & 7) ^ lr) * 8;
    int sw = l15 & 7;
    f32x4 acc[4][4] = {};
    f16x8 af[4][2], bf[4][2];

    const _Float16* Ab = A + (size_t)(bM + w * 32 + lr) * lda + kz + lcs;
    const _Float16* Bb = Bt + (size_t)(bN + w * 32 + lr) * ldb + kz + lcs;
    const int NT = 32;  // K=2048 per slice

#define FF2_STAGE(OB, TN)                                                                \
    {                                                                                    \
        size_t ko = (size_t)(TN) * 64;                                                   \
        _Pragma("unroll") for (int i = 0; i < 4; ++i) {                                  \
            __builtin_amdgcn_global_load_lds(                                            \
                (const __attribute__((address_space(1))) void*)(Ab + (size_t)(i * 8) * lda + ko), \
                (__attribute__((address_space(3))) void*)(&As[OB][w * 32 + i * 8][0]), 16, 0, 0); \
            __builtin_amdgcn_global_load_lds(                                            \
                (const __attribute__((address_space(1))) void*)(Bb + (size_t)(i * 8) * ldb + ko), \
                (__attribute__((address_space(3))) void*)(&Bs[OB][w * 32 + i * 8][0]), 16, 0, 0); \
        }                                                                                \
    }

    FF2_STAGE(0, 0);
    asm volatile("s_waitcnt vmcnt(0)" ::: "memory");
    __builtin_amdgcn_s_barrier();

    int cur = 0;
    for (int t = 0; t < NT; ++t) {
        int nxt = cur ^ 1;
        int tn = (t + 1 < NT) ? t + 1 : 0;  // last iter: dummy re-stage (never read)
        FF2_STAGE(nxt, tn);
#pragma unroll
        for (int i = 0; i < 4; ++i) {
#pragma unroll
            for (int ks = 0; ks < 2; ++ks)
                af[i][ks] = *(const f16x8*)(&As[cur][wr + i * 16 + l15][((ks * 4 + quad) ^ sw) * 8]);
        }
#pragma unroll
        for (int jj = 0; jj < 4; ++jj) {
#pragma unroll
            for (int ks = 0; ks < 2; ++ks)
                bf[jj][ks] = *(const f16x8*)(&Bs[cur][wc + jj * 16 + l15][((ks * 4 + quad) ^ sw) * 8]);
        }
#pragma unroll
        for (int ks = 0; ks < 2; ++ks)
#pragma unroll
            for (int i = 0; i < 4; ++i)
#pragma unroll
                for (int jj = 0; jj < 4; ++jj)
                    acc[i][jj] = __builtin_amdgcn_mfma_f32_16x16x32_f16(af[i][ks], bf[jj][ks], acc[i][jj], 0, 0, 0);
        asm volatile("s_waitcnt vmcnt(0)" ::: "memory");
        __builtin_amdgcn_s_barrier();
        cur = nxt;
    }

    _Float16* pout = zz ? p1 : p0;
#pragma unroll
    for (int i = 0; i < 4; ++i)
#pragma unroll
        for (int jj = 0; jj < 4; ++jj)
#pragma unroll
            for (int r = 0; r < 4; ++r) {
                int row = bM + wr + i * 16 + quad * 4 + r;
                int col = bN + wc + jj * 16 + l15;
                pout[(size_t)row * N + col] = (_Float16)acc[i][jj][r];
            }
}

// ---------------- GEMM 128Mx64N, single-buffer (R4 version), XOR swizzle ------------
// MODE 2: out f16 = resid(f32) + alpha*(acc+bias)          (attn proj -> xmid)
// MODE 4: out f32 = acc                                    (FF2 pass a, fallback)
// MODE 5: out f32 = resid(f16) + alpha*(out + acc + bias)  (FF2 pass b, fallback)
template <int MODE>
__global__ __launch_bounds__(256) void gemm64(const _Float16* __restrict__ A,
                                              const _Float16* __restrict__ Bt,
                                              const float* __restrict__ bias,
                                              void* __restrict__ outp,
                                              const void* __restrict__ residp,
                                              const float* __restrict__ alphap,
                                              int M, int N, int K, int lda, int ldb) {
    __shared__ _Float16 As[128][64];
    __shared__ _Float16 Bs[64][64];
    int tid = threadIdx.x;
    int lane = tid & 63, w = tid >> 6;
    int quad = lane >> 4, l15 = lane & 15;
    int wm = w * 32;
    int bM = blockIdx.y * 128, bN = blockIdx.x * 64;
    int lr = lane >> 3;
    int lcs = ((lane & 7) ^ lr) * 8;
    int sw = l15 & 7;
    f32x4 acc[2][4] = {};

    const _Float16* Abase = A + (size_t)(bM + w * 32 + lr) * lda + lcs;
    const _Float16* Bbase = Bt + (size_t)(bN + w * 16 + lr) * ldb + lcs;

    for (int kt = 0; kt < K; kt += 64) {
#pragma unroll
        for (int i = 0; i < 4; ++i)
            __builtin_amdgcn_global_load_lds(
                (const __attribute__((address_space(1))) void*)(Abase + (size_t)(i * 8) * lda + kt),
                (__attribute__((address_space(3))) void*)(&As[w * 32 + i * 8][0]), 16, 0, 0);
#pragma unroll
        for (int i = 0; i < 2; ++i)
            __builtin_amdgcn_global_load_lds(
                (const __attribute__((address_space(1))) void*)(Bbase + (size_t)(i * 8) * ldb + kt),
                (__attribute__((address_space(3))) void*)(&Bs[w * 16 + i * 8][0]), 16, 0, 0);
        __syncthreads();
#pragma unroll
        for (int ks = 0; ks < 2; ++ks) {
            int sc = ((ks * 4 + quad) ^ sw) * 8;
            f16x8 af[2], bf[4];
#pragma unroll
            for (int i = 0; i < 2; ++i)
                af[i] = *(const f16x8*)(&As[wm + i * 16 + l15][sc]);
#pragma unroll
            for (int j = 0; j < 4; ++j)
                bf[j] = *(const f16x8*)(&Bs[j * 16 + l15][sc]);
#pragma unroll
            for (int i = 0; i < 2; ++i)
#pragma unroll
                for (int j = 0; j < 4; ++j)
                    acc[i][j] = __builtin_amdgcn_mfma_f32_16x16x32_f16(af[i], bf[j], acc[i][j], 0, 0, 0);
        }
        __syncthreads();
    }

    float alpha = 0.f;
    if (MODE == 2 || MODE == 5) alpha = alphap[0];
#pragma unroll
    for (int i = 0; i < 2; ++i)
#pragma unroll
        for (int j = 0; j < 4; ++j)
#pragma unroll
            for (int r = 0; r < 4; ++r) {
                int row = bM + wm + i * 16 + quad * 4 + r;
                int col = bN + j * 16 + l15;
                size_t idx = (size_t)row * N + col;
                if (MODE == 4) {
                    ((float*)outp)[idx] = acc[i][j][r];
                } else if (MODE == 2) {
                    float vv = acc[i][j][r] + bias[col];
                    float rsd = ((const float*)residp)[idx];
                    ((_Float16*)outp)[idx] = (_Float16)(rsd + alpha * vv);
                } else {  // MODE 5
                    float vv = acc[i][j][r] + bias[col];
                    float prev = ((float*)outp)[idx];
                    float rsd = (float)((const _Float16*)residp)[idx];
                    ((float*)outp)[idx] = rsd + alpha * (prev + vv);
                }
            }
}

// ---------------- FF2 reduce: d_out = xmid + alpha*(p0+p1+b2), vectorized x8 --------
__global__ __launch_bounds__(256) void ff2_reduce_kernel(const _Float16* __restrict__ p0,
                                                         const _Float16* __restrict__ p1,
                                                         const _Float16* __restrict__ xmid,
                                                         const float* __restrict__ b2,
                                                         const float* __restrict__ alphap,
                                                         float* __restrict__ out) {
    int i = (blockIdx.x * 256 + threadIdx.x) * 8;
    float alpha = alphap[0];
    f16x8 a = *(const f16x8*)(p0 + i);
    f16x8 b = *(const f16x8*)(p1 + i);
    f16x8 xm = *(const f16x8*)(xmid + i);
    int col = i & 1023;
#pragma unroll
    for (int k = 0; k < 8; ++k)
        out[i + k] = (float)xm[k] + alpha * ((float)a[k] + (float)b[k] + b2[col + k]);
}

// ---------------- MFMA flash attention: balanced 8-wave, 2 q-tiles/block ------------
#define QT 64
#define NEG_BIG (-1e30f)
__global__ __launch_bounds__(512) void attn_mfma_kernel(const _Float16* __restrict__ qkv,
                                                        const _Float16* __restrict__ VtG,
                                                        _Float16* __restrict__ O) {
    __shared__ _Float16 Ks[64][72];
    __shared__ _Float16 Vt[64][72];
    __shared__ _Float16 Ps[8][16][68];
    int tid = threadIdx.x;
    int lane = tid & 63, w = tid >> 6;     // w in 0..7
    int quad = lane >> 4, l15 = lane & 15;
    int bh = blockIdx.x;
    int b = bh >> 4, h = bh & 15;
    int y = blockIdx.y;                    // 0..15
    int seg = w >> 2, ws = w & 3;          // seg 0: long q-tile, seg 1: short
    int qt = seg ? y : (31 - y);
    int q0 = qt * QT;
    int ntw = qt + 1;                      // K-tiles THIS wave computes
    int ntmax = 32 - y;                    // K-tiles staged (= long wave's ntw)
    const _Float16* Qh = qkv + (size_t)b * TT * QKVS + h * HD;
    const _Float16* Kh = Qh + 1024;
    const _Float16* Vrows = VtG + (size_t)bh * HD * TT;

    int m0 = q0 + ws * 16;
    f16x8 aq0 = *(const f16x8*)(Qh + (size_t)(m0 + l15) * QKVS + quad * 8);
    f16x8 aq1 = *(const f16x8*)(Qh + (size_t)(m0 + l15) * QKVS + 32 + quad * 8);

    f32x4 Oacc[4] = {};
    float lrow[4] = {0.f, 0.f, 0.f, 0.f};

    // staging: 512 threads cover 64 rows x 64 cols, one f16x8 each per buffer
    int rr = tid >> 3;                     // 0..63
    int c8 = (tid & 7) * 8;
    const _Float16* Kp = Kh + (size_t)rr * QKVS + c8;
    const _Float16* Vp = Vrows + (size_t)rr * TT + c8;

    f16x8 kreg = *(const f16x8*)(Kp);
    f16x8 vreg = *(const f16x8*)(Vp);

    for (int t = 0; t < ntmax; ++t) {
        int t0 = t * 64;
        __syncthreads();
        *(f16x8*)(&Ks[rr][c8]) = kreg;
        *(f16x8*)(&Vt[rr][c8]) = vreg;
        __syncthreads();
        if (t + 1 < ntmax) {
            kreg = *(const f16x8*)(Kp + (size_t)(t0 + 64) * QKVS);
            vreg = *(const f16x8*)(Vp + t0 + 64);
        }
        if (t >= ntw) continue;           // short-seg waves: stage+barrier only

        f32x4 Sacc[4] = {};
        __builtin_amdgcn_s_setprio(1);
#pragma unroll
        for (int nc = 0; nc < 4; ++nc) {
            f16x8 bk0 = *(const f16x8*)(&Ks[nc * 16 + l15][quad * 8]);
            f16x8 bk1 = *(const f16x8*)(&Ks[nc * 16 + l15][32 + quad * 8]);
            Sacc[nc] = __builtin_amdgcn_mfma_f32_16x16x32_f16(aq0, bk0, Sacc[nc], 0, 0, 0);
            Sacc[nc] = __builtin_amdgcn_mfma_f32_16x16x32_f16(aq1, bk1, Sacc[nc], 0, 0, 0);
        }
        __builtin_amdgcn_s_setprio(0);

        if (t0 == q0) {  // diagonal tile: causal mask
#pragma unroll
            for (int nc = 0; nc < 4; ++nc) {
                int key = t0 + nc * 16 + l15;
#pragma unroll
                for (int i = 0; i < 4; ++i)
                    if (key > m0 + quad * 4 + i) Sacc[nc][i] = NEG_BIG;
            }
        }

        // P = exp2(S) (no max subtraction), accumulate per-lane l
#pragma unroll
        for (int nc = 0; nc < 4; ++nc)
#pragma unroll
            for (int i = 0; i < 4; ++i) {
                float p = exp2f(Sacc[nc][i]);
                lrow[i] += p;
                Ps[w][quad * 4 + i][nc * 16 + l15] = (_Float16)p;
            }
        __asm__ __volatile__("s_waitcnt lgkmcnt(0)" ::: "memory");  // wave-local roundtrip

        f16x8 ap0 = *(const f16x8*)(&Ps[w][l15][quad * 8]);
        f16x8 ap1 = *(const f16x8*)(&Ps[w][l15][32 + quad * 8]);
        __builtin_amdgcn_s_setprio(1);
#pragma unroll
        for (int nc = 0; nc < 4; ++nc) {
            int d = nc * 16 + l15;
            f16x8 bv0 = *(const f16x8*)(&Vt[d][quad * 8]);
            f16x8 bv1 = *(const f16x8*)(&Vt[d][32 + quad * 8]);
            Oacc[nc] = __builtin_amdgcn_mfma_f32_16x16x32_f16(ap0, bv0, Oacc[nc], 0, 0, 0);
            Oacc[nc] = __builtin_amdgcn_mfma_f32_16x16x32_f16(ap1, bv1, Oacc[nc], 0, 0, 0);
        }
        __builtin_amdgcn_s_setprio(0);
    }

#pragma unroll
    for (int off = 1; off < 16; off <<= 1)
#pragma unroll
        for (int i = 0; i < 4; ++i) lrow[i] += __shfl_xor(lrow[i], off);
#pragma unroll
    for (int i = 0; i < 4; ++i) lrow[i] = 1.0f / lrow[i];
    _Float16* Oh = O + (size_t)b * TT * EMB + h * HD;
#pragma unroll
    for (int nc = 0; nc < 4; ++nc)
#pragma unroll
        for (int i = 0; i < 4; ++i) {
            int row = m0 + quad * 4 + i;
            Oh[(size_t)row * EMB + nc * 16 + l15] = (_Float16)(Oacc[nc][i] * lrow[i]);
        }
}

extern "C" void kernel_launch(void* const* d_in, const int* in_sizes, int n_in,
                              void* d_out, int out_size, void* d_ws, size_t ws_size,
                              hipStream_t stream) {
    const float* x = (const float*)d_in[0];
    const float* wq = (const float*)d_in[1];
    const float* bq = (const float*)d_in[2];
    const float* wk = (const float*)d_in[3];
    const float* bk = (const float*)d_in[4];
    const float* wv = (const float*)d_in[5];
    const float* bv = (const float*)d_in[6];
    const float* wo = (const float*)d_in[7];
    const float* bo = (const float*)d_in[8];
    const float* w1 = (const float*)d_in[9];
    const float* b1 = (const float*)d_in[10];
    const float* w2 = (const float*)d_in[11];
    const float* b2 = (const float*)d_in[12];
    const float* ln1_g = (const float*)d_in[13];
    const float* ln1_b = (const float*)d_in[14];
    const float* ln2_g = (const float*)d_in[15];
    const float* ln2_b = (const float*)d_in[16];
    const float* alpha_attn = (const float*)d_in[17];
    const float* alpha_ff = (const float*)d_in[18];

    const size_t SL = (size_t)8 * 1024 * 1024;
    char* ws = (char*)d_ws;
    _Float16* xn = (_Float16*)(ws);
    _Float16* qkv = (_Float16*)(ws + SL);
    _Float16* wqkvT = (_Float16*)(ws + 4 * SL);
    float* qkvbias = (float*)(ws + 4 * SL + 6 * 1024 * 1024);
    _Float16* attnout = (_Float16*)(ws);
    _Float16* xmid = (_Float16*)(ws + SL);
    _Float16* x2 = (_Float16*)(ws + 2 * SL);
    _Float16* w1T = (_Float16*)(ws);
    _Float16* w2T = (_Float16*)(ws + 3 * SL);
    _Float16* ff1 = (_Float16*)(ws + 4 * SL);
    bool bigws = ws_size >= (size_t)64 * 1024 * 1024;
    // bigws: VtG=S5, woT=S6 (no aliasing with wqkvT during QKV, fused vT OK).
    // fallback (48MB): VtG=S4 (overwrites wqkvT AFTER QKV via separate vT kernel),
    //                  woT=S5; fused vT disabled (would alias wqkvT mid-GEMM).
    _Float16* VtG = bigws ? (_Float16*)(ws + 5 * SL) : (_Float16*)(ws + 4 * SL);
    _Float16* woT = bigws ? (_Float16*)(ws + 6 * SL) : (_Float16*)(ws + 5 * SL);
    // FF2 partials: S0 (attnout dead) and S2 (x2 dead after FF1). Do NOT use S5/S6:
    // ff1 is 32MB spanning S4..S8 and is gemm_ff2's live A operand (R8 bug).
    _Float16* part0 = (_Float16*)(ws);
    _Float16* part1 = (_Float16*)(ws + 2 * SL);

    prep0_kernel<<<8204, 256, 0, stream>>>(x, xn, ln1_g, ln1_b, wq, wk, wv, wo,
                                           bq, bk, bv, wqkvT, woT, qkvbias);

    if (bigws) {
        gemm256<1><<<dim3(QKVS / 256, NTOK / 256), 512, 0, stream>>>(
            xn, wqkvT, qkvbias, qkv, (void*)VtG, NTOK, QKVS, EMB, EMB, EMB);
    } else {
        gemm_f16t<6><<<dim3(QKVS / 128, NTOK / 128), 256, 0, stream>>>(
            xn, wqkvT, qkvbias, qkv, nullptr, NTOK, QKVS, EMB, EMB, EMB);
        vT_kernel<<<dim3(TT / 64, BB * NH), 256, 0, stream>>>(qkv, VtG);
    }

    attn_mfma_kernel<<<dim3(BB * NH, TT / QT / 2), 512, 0, stream>>>(qkv, VtG, attnout);

    gemm64<2><<<dim3(EMB / 64, NTOK / 128), 256, 0, stream>>>(
        attnout, woT, bo, xmid, x, alpha_attn, NTOK, EMB, EMB, EMB, EMB);

    // merged LN2 + w1/w2 transpose: one launch instead of two
    lnprep2_kernel<<<12288, 256, 0, stream>>>(xmid, x2, ln2_g, ln2_b, w1, w2, w1T, w2T);

    if (bigws) {
        gemm256<0><<<dim3(FF_DIM / 256, NTOK / 256), 512, 0, stream>>>(
            x2, w1T, b1, ff1, nullptr, NTOK, FF_DIM, EMB, EMB, EMB);
        gemm_ff2<<<512, 256, 0, stream>>>(
            ff1, w2T, part0, part1, NTOK, EMB, FF_DIM, FF_DIM, FF_DIM);
        ff2_reduce_kernel<<<NTOK * EMB / 8 / 256, 256, 0, stream>>>(
            part0, part1, xmid, b2, alpha_ff, (float*)d_out);
    } else {
        const int NC = 2048;
        for (int hh = 0; hh < 2; ++hh) {
            const _Float16* w1Th = w1T + (size_t)hh * NC * EMB;
            const _Float16* w2Th = w2T + (size_t)hh * NC;
            gemm_f16t<1><<<dim3(NC / 128, NTOK / 128), 256, 0, stream>>>(
                x2, w1Th, b1 + hh * NC, ff1, nullptr, NTOK, NC, EMB, EMB, EMB);
            if (hh == 0)
                gemm64<4><<<dim3(EMB / 64, NTOK / 128), 256, 0, stream>>>(
                    ff1, w2Th, nullptr, d_out, nullptr, nullptr, NTOK, EMB, NC, NC, FF_DIM);
            else
                gemm64<5><<<dim3(EMB / 64, NTOK / 128), 256, 0, stream>>>(
                    ff1, w2Th, b2, d_out, xmid, alpha_ff, NTOK, EMB, NC, NC, FF_DIM);
        }
    }
}